// Round 1
// baseline (28908.624 us; speedup 1.0000x reference)
//
#include <hip/hip_runtime.h>
#include <math.h>

// ---------------- problem dims ----------------
constexpr int Bb = 128, Tt = 256, Dd = 64, Hh = 512, Cc = 10;
constexpr float MISSINGV = 128.0f;

#define NBLK 256
#define NTHR 256

// ---------------- workspace layout (bytes) ----------------
constexpr size_t WS_CNT   = 0;                      // unsigned barrier counter
constexpr size_t WS_PLOSS = 64;                     // float pred-loss accumulator
constexpr size_t WS_REG   = 128;                    // float reg accumulator
constexpr size_t WS_PRED  = 256;                    // pred_buf [128][64] f32 = 32768
constexpr size_t WS_H     = WS_PRED + 32768;        // h_buf [128][512] f32 = 262144
constexpr size_t WS_WT    = WS_H + 262144;          // wt_perm [32][512][64] f32 = 4 MB
constexpr size_t WS_KT    = WS_WT + 4194304;        // kt_perm [32][64][64] f32 = 512 KB
constexpr size_t WS_TOTAL = WS_KT + 524288;

// ---------------- LDS layout ----------------
constexpr int HT_STRIDE = 516;                      // hT [16][516] floats (pad keeps 16B align, spreads banks)
constexpr int XIN_STRIDE = 68;
constexpr int ZB_RSTRIDE = 68;                      // zbuf row stride (floats)
constexpr int ZB_WSTRIDE = 16 * ZB_RSTRIDE;         // per-wave stride = 1088 floats
constexpr size_t SM_HT    = 0;                      // 33024 B  (aliased: zbuf 17408 B, final dense_W 20480 B)
constexpr size_t SM_XIN   = 33024;                  // 4352 B   (aliased: pbuf 512 B)
constexpr size_t SM_WCOL  = SM_XIN + 4352;          // [512][2] = 4096 B
constexpr size_t SM_RED   = SM_WCOL + 4096;         // 64 B scratch
constexpr size_t SM_TOTAL = SM_RED + 64;            // 41536 B

// ---------------- weight permutation kernel ----------------
// wt_perm[ht][k][uu] , uu = u*4+g  -> rkernel[k][g*512 + ht*16 + u]
// kt_perm[ht][d][uu]               -> kernel [d][g*512 + ht*16 + u]
__global__ void perm_weights(const float* __restrict__ rk, const float* __restrict__ kern,
                             float* __restrict__ wtp, float* __restrict__ ktp) {
    int o = blockIdx.x * 256 + threadIdx.x;
    if (o < 32 * 512 * 64) {
        int uu = o & 63, k = (o >> 6) & 511, ht = o >> 15;
        int u = uu >> 2, g = uu & 3;
        wtp[o] = rk[k * 2048 + g * 512 + ht * 16 + u];
    }
    if (o < 32 * 64 * 64) {
        int uu = o & 63, d = (o >> 6) & 63, ht = o >> 12;
        int u = uu >> 2, g = uu & 3;
        ktp[o] = kern[d * 2048 + g * 512 + ht * 16 + u];
    }
}

__device__ __forceinline__ float sigmoidf_(float v) { return 1.0f / (1.0f + expf(-v)); }

// ---------------- persistent scan kernel ----------------
__launch_bounds__(NTHR, 1)
__global__ void ajrnn_persistent(
    const float* __restrict__ x, const float* __restrict__ tgt, const float* __restrict__ msk,
    const float* __restrict__ lbl, const float* __restrict__ W, const float* __restrict__ bias,
    const float* __restrict__ kern, const float* __restrict__ rkern, const float* __restrict__ lbias,
    const float* __restrict__ dW, const float* __restrict__ db,
    float* __restrict__ out, unsigned char* __restrict__ ws)
{
    __shared__ __align__(16) unsigned char smem[SM_TOTAL];
    float* hT    = (float*)(smem + SM_HT);
    float* xin   = (float*)(smem + SM_XIN);
    float* pbuf  = xin;                 // alias: phase-A only
    float* zbuf  = hT;                  // alias: phase-B only
    float* Wcol  = (float*)(smem + SM_WCOL);
    float* redsc = (float*)(smem + SM_RED);

    unsigned* cnt    = (unsigned*)(ws + WS_CNT);
    float* ploss_acc = (float*)(ws + WS_PLOSS);
    float* reg_acc   = (float*)(ws + WS_REG);
    float* pred_buf  = (float*)(ws + WS_PRED);
    float* h_buf     = (float*)(ws + WS_H);
    const float* wt_perm = (const float*)(ws + WS_WT);
    const float* kt_perm = (const float*)(ws + WS_KT);

    const int tid = threadIdx.x;
    const int bid = blockIdx.x;
    const int rt = bid >> 5, ht = bid & 31;      // 8 row-tiles x 32 hidden-tiles
    const int r0 = rt * 16, j0 = ht * 16;
    const int wave = tid >> 6, lane = tid & 63;
    const int zr = lane & 15;                    // z-loop row (0..15)
    const int uq = lane >> 4;                    // unit-quad (0..3)
    const int cr = tid >> 4;                     // combine row (0..15)
    const int cu = tid & 15;                     // combine unit (0..15)

    unsigned bar = 0;
    auto gbar = [&]() {
        bar += NBLK;
        __threadfence();
        __syncthreads();
        if (tid == 0) {
            atomicAdd(cnt, 1u);
            while (__hip_atomic_load(cnt, __ATOMIC_RELAXED, __HIP_MEMORY_SCOPE_AGENT) < bar)
                __builtin_amdgcn_s_sleep(1);
        }
        __syncthreads();
        __threadfence();
    };

    // ---- setup: stage W columns (d = 2*ht, 2*ht+1), per-thread biases ----
    for (int i = tid; i < Hh * 2; i += NTHR)
        Wcol[i] = W[(i >> 1) * Dd + 2 * ht + (i & 1)];
    const float pbias = bias[2 * ht + ((lane >> 4) & 1)];
    const int ju = j0 + cu;
    const float lb0 = lbias[ju], lb1 = lbias[Hh + ju], lb2 = lbias[2 * Hh + ju], lb3 = lbias[3 * Hh + ju];

    // ---- L2 regularization: sum of squares over all params ----
    {
        float rs = 0.f;
        const float* arrs[7] = {W, bias, kern, rkern, lbias, dW, db};
        const int lens[7] = {Hh * Dd, Dd, Dd * 4 * Hh, Hh * 4 * Hh, 4 * Hh, Hh * Cc, Cc};
        for (int a = 0; a < 7; ++a) {
            const float* p = arrs[a]; const int n = lens[a];
            for (int i = bid * NTHR + tid; i < n; i += NBLK * NTHR) { float v = p[i]; rs += v * v; }
        }
        #pragma unroll
        for (int off = 32; off > 0; off >>= 1) rs += __shfl_down(rs, off);
        if (lane == 0) redsc[wave] = rs;
        __syncthreads();
        if (tid == 0) atomicAdd(reg_acc, redsc[0] + redsc[1] + redsc[2] + redsc[3]);
        __syncthreads();
    }

    float c_reg = 0.f;          // this thread's persistent cell state (row cr, unit cu)
    float lacc = 0.f;           // pred-loss accumulator (wave0 lanes<32)
    float acc[4][4];            // z partials: [c4][gate]; cols = uq*16 + c4*4 + gate

    const float* wtp = wt_perm + (size_t)ht * 512 * 64;
    const float* ktp = kt_perm + (size_t)ht * 64 * 64;

    auto do_zx = [&]() {        // x_in @ kernel for this wave's d-range (accumulates into acc)
        const int dbeg = wave * 16;
        for (int d = dbeg; d < dbeg + 16; d += 4) {
            float4 xv4 = *(const float4*)&xin[zr * XIN_STRIDE + d];
            float xa[4] = {xv4.x, xv4.y, xv4.z, xv4.w};
            #pragma unroll
            for (int dd = 0; dd < 4; ++dd) {
                const float4* kd = (const float4*)&ktp[(size_t)(d + dd) * 64] + uq * 4;
                #pragma unroll
                for (int c4 = 0; c4 < 4; ++c4) {
                    float4 kv = kd[c4];
                    acc[c4][0] += xa[dd] * kv.x; acc[c4][1] += xa[dd] * kv.y;
                    acc[c4][2] += xa[dd] * kv.z; acc[c4][3] += xa[dd] * kv.w;
                }
            }
        }
    };
    auto store_zbuf = [&]() {
        #pragma unroll
        for (int c4 = 0; c4 < 4; ++c4) {
            float4 v = {acc[c4][0], acc[c4][1], acc[c4][2], acc[c4][3]};
            *(float4*)&zbuf[wave * ZB_WSTRIDE + zr * ZB_RSTRIDE + (uq * 4 + c4) * 4] = v;
        }
    };
    auto combine = [&]() {      // z = sum of 4 wave partials + bias -> gates -> c,h
        float4 z = {lb0, lb1, lb2, lb3};
        #pragma unroll
        for (int w = 0; w < 4; ++w) {
            float4 v = *(const float4*)&zbuf[w * ZB_WSTRIDE + cr * ZB_RSTRIDE + cu * 4];
            z.x += v.x; z.y += v.y; z.z += v.z; z.w += v.w;
        }
        float si = sigmoidf_(z.x), sf = sigmoidf_(z.y), so = sigmoidf_(z.w);
        c_reg = sf * c_reg + si * tanhf(z.z);
        float hv = so * tanhf(c_reg);
        h_buf[(size_t)(r0 + cr) * Hh + j0 + cu] = hv;
    };

    // ---------------- step 0: raw x0, no imputation, h0=c0=0 ----------------
    for (int i = tid; i < 16 * Dd; i += NTHR) {
        int rr = i >> 6, d = i & 63;
        xin[rr * XIN_STRIDE + d] = x[((size_t)(r0 + rr) * Tt + 0) * Dd + d];
    }
    #pragma unroll
    for (int a = 0; a < 4; ++a)
        #pragma unroll
        for (int b2 = 0; b2 < 4; ++b2) acc[a][b2] = 0.f;
    __syncthreads();
    do_zx();
    __syncthreads();
    store_zbuf();
    __syncthreads();
    combine();
    gbar();

    // ---------------- steps t = 1..255 ----------------
    for (int t = 1; t < Tt; ++t) {
        // ---- phase A: stage h_t, pred partials, z_r = h @ rkernel ----
        for (int i = tid; i < 16 * 128; i += NTHR) {
            int k4 = i & 127, rr = i >> 7;
            float4 hv = *(const float4*)&h_buf[(size_t)(r0 + rr) * Hh + k4 * 4];
            *(float4*)&hT[rr * HT_STRIDE + k4 * 4] = hv;
        }
        __syncthreads();
        {   // pred partial over this wave's k-range (lanes: r=lane&15, dl=(lane>>4)&1, kh=lane>>5)
            const int pr = lane & 15, pdl = (lane >> 4) & 1, pkh = lane >> 5;
            float s = 0.f;
            const int kb = wave * 128 + pkh * 64;
            for (int k = kb; k < kb + 64; ++k)
                s += hT[pr * HT_STRIDE + k] * Wcol[k * 2 + pdl];
            s += __shfl_down(s, 32);
            if (lane < 32) pbuf[wave * 32 + lane] = s;
        }
        #pragma unroll
        for (int a = 0; a < 4; ++a)
            #pragma unroll
            for (int b2 = 0; b2 < 4; ++b2) acc[a][b2] = 0.f;
        {   // z_r over this wave's k-range
            const int kb = wave * 128;
            for (int k = kb; k < kb + 128; k += 4) {
                float4 hv4 = *(const float4*)&hT[zr * HT_STRIDE + k];
                float ha[4] = {hv4.x, hv4.y, hv4.z, hv4.w};
                #pragma unroll
                for (int kk = 0; kk < 4; ++kk) {
                    const float4* wk = (const float4*)&wtp[(size_t)(k + kk) * 64] + uq * 4;
                    #pragma unroll
                    for (int c4 = 0; c4 < 4; ++c4) {
                        float4 wv = wk[c4];
                        acc[c4][0] += ha[kk] * wv.x; acc[c4][1] += ha[kk] * wv.y;
                        acc[c4][2] += ha[kk] * wv.z; acc[c4][3] += ha[kk] * wv.w;
                    }
                }
            }
        }
        __syncthreads();
        if (wave == 0 && lane < 32) {   // finalize pred, write it, accumulate loss
            float p = pbuf[lane] + pbuf[32 + lane] + pbuf[64 + lane] + pbuf[96 + lane] + pbias;
            int rr = lane & 15, dl = lane >> 4;
            int d = 2 * ht + dl;
            pred_buf[(size_t)(r0 + rr) * Dd + d] = p;
            size_t ix = ((size_t)(r0 + rr) * (Tt - 1) + (t - 1)) * Dd + d;
            float e = (tgt[ix] - p) * msk[ix];
            lacc += e * e;
        }
        gbar();

        // ---- phase B: impute, z_x, gates, h update ----
        for (int i = tid; i < 16 * Dd; i += NTHR) {
            int rr = i >> 6, d = i & 63;
            float xv = x[((size_t)(r0 + rr) * Tt + t) * Dd + d];
            float pv = pred_buf[(size_t)(r0 + rr) * Dd + d];
            xin[rr * XIN_STRIDE + d] = (xv == MISSINGV) ? pv : xv;
        }
        __syncthreads();
        do_zx();
        __syncthreads();
        store_zbuf();
        __syncthreads();
        combine();
        gbar();
    }

    // ---------------- epilogue ----------------
    if (wave == 0) {
        #pragma unroll
        for (int off = 16; off > 0; off >>= 1) lacc += __shfl_down(lacc, off);
        if (lane == 0) atomicAdd(ploss_acc, lacc);
    }
    gbar();

    if (bid == 0) {
        float* dwl = (float*)smem;                 // [512][10] staged dense_W
        for (int i = tid; i < Hh * Cc; i += NTHR) dwl[i] = dW[i];
        __syncthreads();
        if (tid < Bb) {
            float a[Cc];
            #pragma unroll
            for (int c = 0; c < Cc; ++c) a[c] = db[c];
            for (int k = 0; k < Hh; ++k) {
                float hv = h_buf[(size_t)tid * Hh + k];
                #pragma unroll
                for (int c = 0; c < Cc; ++c) a[c] += hv * dwl[k * Cc + c];
            }
            float m = a[0];
            #pragma unroll
            for (int c = 1; c < Cc; ++c) m = fmaxf(m, a[c]);
            float s = 0.f;
            #pragma unroll
            for (int c = 0; c < Cc; ++c) s += expf(a[c] - m);
            float lse = m + logf(s);
            float lc = 0.f;
            #pragma unroll
            for (int c = 0; c < Cc; ++c) lc += lbl[tid * Cc + c] * (lse - a[c]);
            float pl = __hip_atomic_load(ploss_acc, __ATOMIC_RELAXED, __HIP_MEMORY_SCOPE_AGENT);
            float rg = __hip_atomic_load(reg_acc, __ATOMIC_RELAXED, __HIP_MEMORY_SCOPE_AGENT);
            // loss_pred = sum / (B*(T-1)*D) / B ; reg = 0.5*sum(sq) ; LAMDA=1, REG_COEF=1e-4
            out[tid] = lc + pl * (1.0f / (2088960.0f * 128.0f)) + 1e-4f * 0.5f * rg;
        }
    }
}

extern "C" void kernel_launch(void* const* d_in, const int* in_sizes, int n_in,
                              void* d_out, int out_size, void* d_ws, size_t ws_size,
                              hipStream_t stream) {
    const float* x     = (const float*)d_in[0];
    const float* tgt   = (const float*)d_in[1];
    const float* msk   = (const float*)d_in[2];
    const float* lbl   = (const float*)d_in[3];
    const float* W     = (const float*)d_in[4];
    const float* bias  = (const float*)d_in[5];
    const float* kern  = (const float*)d_in[6];
    const float* rkern = (const float*)d_in[7];
    const float* lbias = (const float*)d_in[8];
    const float* dW    = (const float*)d_in[9];
    const float* db    = (const float*)d_in[10];
    unsigned char* ws  = (unsigned char*)d_ws;

    // zero barrier counter + loss accumulators (re-done every call; graph-capture safe)
    hipMemsetAsync(d_ws, 0, 256, stream);
    perm_weights<<<4096, 256, 0, stream>>>(rkern, kern, (float*)(ws + WS_WT), (float*)(ws + WS_KT));
    ajrnn_persistent<<<NBLK, NTHR, 0, stream>>>(x, tgt, msk, lbl, W, bias, kern, rkern, lbias,
                                                dW, db, (float*)d_out, ws);
}

// Round 2
// 9799.420 us; speedup vs baseline: 2.9500x; 2.9500x over previous
//
#include <hip/hip_runtime.h>
#include <math.h>

// ---------------- problem dims ----------------
constexpr int Bb = 128, Tt = 256, Dd = 64, Hh = 512, Cc = 10;
constexpr float MISSINGV = 128.0f;

#define NBLK 256
#define NTHR 256

// ---------------- workspace layout (bytes) ----------------
constexpr size_t WS_CNT   = 0;                      // unsigned barrier counter
constexpr size_t WS_PLOSS = 64;                     // float pred-loss accumulator
constexpr size_t WS_REG   = 128;                    // float reg accumulator
constexpr size_t WS_PRED  = 256;                    // pred_buf [128][64] f32 = 32768
constexpr size_t WS_H     = WS_PRED + 32768;        // h_buf [128][512] f32 = 262144
constexpr size_t WS_WT    = WS_H + 262144;          // wt_perm [32][512][64] f32 = 4 MB
constexpr size_t WS_KT    = WS_WT + 4194304;        // kt_perm [32][64][64] f32 = 512 KB
constexpr size_t WS_TOTAL = WS_KT + 524288;

// ---------------- LDS layout ----------------
constexpr int HT_STRIDE = 516;                      // hT [16][516] floats
constexpr int XIN_STRIDE = 68;
constexpr int ZB_RSTRIDE = 68;                      // zbuf row stride (floats)
constexpr int ZB_WSTRIDE = 16 * ZB_RSTRIDE;         // per-wave stride = 1088 floats
constexpr size_t SM_HT    = 0;                      // 33024 B (aliased: zbuf / final dense_W)
constexpr size_t SM_XIN   = 33024;                  // 4352 B (aliased: pbuf)
constexpr size_t SM_WCOL  = SM_XIN + 4352;          // [512][2] = 4096 B
constexpr size_t SM_RED   = SM_WCOL + 4096;         // 64 B scratch
constexpr size_t SM_TOTAL = SM_RED + 64;            // 41536 B

// ---- agent-scope coherent (cache-bypassing, sc0 sc1) accessors ----
// These are the ONLY accesses used for cross-block data (h_buf, pred_buf,
// counters). No __threadfence anywhere: a device-scope fence lowers to
// buffer_wbl2 + buffer_inv (full L2 flush) and was the round-1 disaster
// (442 MB HBM refetch/step, VALUBusy 2.7%).
__device__ __forceinline__ float coh_ld(const float* p) {
    return __hip_atomic_load(p, __ATOMIC_RELAXED, __HIP_MEMORY_SCOPE_AGENT);
}
__device__ __forceinline__ void coh_st(float* p, float v) {
    __hip_atomic_store(p, v, __ATOMIC_RELAXED, __HIP_MEMORY_SCOPE_AGENT);
}

// ---------------- weight permutation kernel ----------------
__global__ void perm_weights(const float* __restrict__ rk, const float* __restrict__ kern,
                             float* __restrict__ wtp, float* __restrict__ ktp) {
    int o = blockIdx.x * 256 + threadIdx.x;
    if (o < 32 * 512 * 64) {
        int uu = o & 63, k = (o >> 6) & 511, ht = o >> 15;
        int u = uu >> 2, g = uu & 3;
        wtp[o] = rk[k * 2048 + g * 512 + ht * 16 + u];
    }
    if (o < 32 * 64 * 64) {
        int uu = o & 63, d = (o >> 6) & 63, ht = o >> 12;
        int u = uu >> 2, g = uu & 3;
        ktp[o] = kern[d * 2048 + g * 512 + ht * 16 + u];
    }
}

__device__ __forceinline__ float sigmoidf_(float v) { return 1.0f / (1.0f + expf(-v)); }

// ---------------- persistent scan kernel ----------------
__launch_bounds__(NTHR, 1)
__global__ void ajrnn_persistent(
    const float* __restrict__ x, const float* __restrict__ tgt, const float* __restrict__ msk,
    const float* __restrict__ lbl, const float* __restrict__ W, const float* __restrict__ bias,
    const float* __restrict__ kern, const float* __restrict__ rkern, const float* __restrict__ lbias,
    const float* __restrict__ dW, const float* __restrict__ db,
    float* __restrict__ out, unsigned char* __restrict__ ws)
{
    __shared__ __align__(16) unsigned char smem[SM_TOTAL];
    float* hT    = (float*)(smem + SM_HT);
    float* xin   = (float*)(smem + SM_XIN);
    float* pbuf  = xin;                 // alias: phase-A only
    float* zbuf  = hT;                  // alias: phase-B only
    float* Wcol  = (float*)(smem + SM_WCOL);
    float* redsc = (float*)(smem + SM_RED);

    unsigned* cnt    = (unsigned*)(ws + WS_CNT);
    float* ploss_acc = (float*)(ws + WS_PLOSS);
    float* reg_acc   = (float*)(ws + WS_REG);
    float* pred_buf  = (float*)(ws + WS_PRED);
    float* h_buf     = (float*)(ws + WS_H);
    const float* wt_perm = (const float*)(ws + WS_WT);
    const float* kt_perm = (const float*)(ws + WS_KT);

    const int tid = threadIdx.x;
    const int bid = blockIdx.x;
    const int rt = bid >> 5, ht = bid & 31;      // 8 row-tiles x 32 hidden-tiles
    const int r0 = rt * 16, j0 = ht * 16;
    const int wave = tid >> 6, lane = tid & 63;
    const int zr = lane & 15;                    // z-loop row (0..15)
    const int uq = lane >> 4;                    // unit-quad (0..3)
    const int cr = tid >> 4;                     // combine row (0..15)
    const int cu = tid & 15;                     // combine unit (0..15)

    unsigned bar = 0;
    auto gbar = [&]() {
        bar += NBLK;
        __syncthreads();        // drains vmcnt(0) per wave before s_barrier
        if (tid == 0) {
            __builtin_amdgcn_s_waitcnt(0);
            __hip_atomic_fetch_add(cnt, 1u, __ATOMIC_RELAXED, __HIP_MEMORY_SCOPE_AGENT);
            while (__hip_atomic_load(cnt, __ATOMIC_RELAXED, __HIP_MEMORY_SCOPE_AGENT) < bar)
                __builtin_amdgcn_s_sleep(1);
        }
        __syncthreads();
    };

    // ---- setup: stage W columns (d = 2*ht, 2*ht+1), per-thread biases ----
    for (int i = tid; i < Hh * 2; i += NTHR)
        Wcol[i] = W[(i >> 1) * Dd + 2 * ht + (i & 1)];
    const float pbias = bias[2 * ht + ((lane >> 4) & 1)];
    const int ju = j0 + cu;
    const float lb0 = lbias[ju], lb1 = lbias[Hh + ju], lb2 = lbias[2 * Hh + ju], lb3 = lbias[3 * Hh + ju];

    // ---- L2 regularization: sum of squares over all params ----
    {
        float rs = 0.f;
        const float* arrs[7] = {W, bias, kern, rkern, lbias, dW, db};
        const int lens[7] = {Hh * Dd, Dd, Dd * 4 * Hh, Hh * 4 * Hh, 4 * Hh, Hh * Cc, Cc};
        for (int a = 0; a < 7; ++a) {
            const float* p = arrs[a]; const int n = lens[a];
            for (int i = bid * NTHR + tid; i < n; i += NBLK * NTHR) { float v = p[i]; rs += v * v; }
        }
        #pragma unroll
        for (int off = 32; off > 0; off >>= 1) rs += __shfl_down(rs, off);
        if (lane == 0) redsc[wave] = rs;
        __syncthreads();
        if (tid == 0) atomicAdd(reg_acc, redsc[0] + redsc[1] + redsc[2] + redsc[3]);
        __syncthreads();
    }

    float c_reg = 0.f;          // this thread's persistent cell state (row cr, unit cu)
    float lacc = 0.f;           // pred-loss accumulator (wave0 lanes<32)
    float acc[4][4];            // z partials: [c4][gate]; cols = uq*16 + c4*4 + gate

    const float* wtp = wt_perm + (size_t)ht * 512 * 64;
    const float* ktp = kt_perm + (size_t)ht * 64 * 64;

    auto do_zx = [&]() {        // x_in @ kernel for this wave's d-range (accumulates into acc)
        const int dbeg = wave * 16;
        for (int d = dbeg; d < dbeg + 16; d += 4) {
            float4 xv4 = *(const float4*)&xin[zr * XIN_STRIDE + d];
            float xa[4] = {xv4.x, xv4.y, xv4.z, xv4.w};
            #pragma unroll
            for (int dd = 0; dd < 4; ++dd) {
                const float4* kd = (const float4*)&ktp[(size_t)(d + dd) * 64] + uq * 4;
                #pragma unroll
                for (int c4 = 0; c4 < 4; ++c4) {
                    float4 kv = kd[c4];
                    acc[c4][0] += xa[dd] * kv.x; acc[c4][1] += xa[dd] * kv.y;
                    acc[c4][2] += xa[dd] * kv.z; acc[c4][3] += xa[dd] * kv.w;
                }
            }
        }
    };
    auto store_zbuf = [&]() {
        #pragma unroll
        for (int c4 = 0; c4 < 4; ++c4) {
            float4 v = {acc[c4][0], acc[c4][1], acc[c4][2], acc[c4][3]};
            *(float4*)&zbuf[wave * ZB_WSTRIDE + zr * ZB_RSTRIDE + (uq * 4 + c4) * 4] = v;
        }
    };
    auto combine = [&]() {      // z = sum of 4 wave partials + bias -> gates -> c,h
        float4 z = {lb0, lb1, lb2, lb3};
        #pragma unroll
        for (int w = 0; w < 4; ++w) {
            float4 v = *(const float4*)&zbuf[w * ZB_WSTRIDE + cr * ZB_RSTRIDE + cu * 4];
            z.x += v.x; z.y += v.y; z.z += v.z; z.w += v.w;
        }
        float si = sigmoidf_(z.x), sf = sigmoidf_(z.y), so = sigmoidf_(z.w);
        c_reg = sf * c_reg + si * tanhf(z.z);
        float hv = so * tanhf(c_reg);
        coh_st(&h_buf[(size_t)(r0 + cr) * Hh + j0 + cu], hv);
    };

    // ---------------- step 0: raw x0, no imputation, h0=c0=0 ----------------
    for (int i = tid; i < 16 * Dd; i += NTHR) {
        int rr = i >> 6, d = i & 63;
        xin[rr * XIN_STRIDE + d] = x[((size_t)(r0 + rr) * Tt + 0) * Dd + d];
    }
    #pragma unroll
    for (int a = 0; a < 4; ++a)
        #pragma unroll
        for (int b2 = 0; b2 < 4; ++b2) acc[a][b2] = 0.f;
    __syncthreads();
    do_zx();
    __syncthreads();
    store_zbuf();
    __syncthreads();
    combine();
    gbar();

    // ---------------- steps t = 1..255 ----------------
    for (int t = 1; t < Tt; ++t) {
        // ---- phase A: stage h_t (coherent scalar loads), pred partials, z_r ----
        #pragma unroll
        for (int j = 0; j < 32; ++j) {
            int i = tid + j * NTHR;            // i in [0, 16*512)
            int rr = i >> 9, k = i & 511;
            hT[rr * HT_STRIDE + k] = coh_ld(&h_buf[(size_t)(r0 + rr) * Hh + k]);
        }
        __syncthreads();
        {   // pred partial over this wave's k-range
            const int pr = lane & 15, pdl = (lane >> 4) & 1, pkh = lane >> 5;
            float s = 0.f;
            const int kb = wave * 128 + pkh * 64;
            for (int k = kb; k < kb + 64; ++k)
                s += hT[pr * HT_STRIDE + k] * Wcol[k * 2 + pdl];
            s += __shfl_down(s, 32);
            if (lane < 32) pbuf[wave * 32 + lane] = s;
        }
        #pragma unroll
        for (int a = 0; a < 4; ++a)
            #pragma unroll
            for (int b2 = 0; b2 < 4; ++b2) acc[a][b2] = 0.f;
        {   // z_r over this wave's k-range
            const int kb = wave * 128;
            for (int k = kb; k < kb + 128; k += 4) {
                float4 hv4 = *(const float4*)&hT[zr * HT_STRIDE + k];
                float ha[4] = {hv4.x, hv4.y, hv4.z, hv4.w};
                #pragma unroll
                for (int kk = 0; kk < 4; ++kk) {
                    const float4* wk = (const float4*)&wtp[(size_t)(k + kk) * 64] + uq * 4;
                    #pragma unroll
                    for (int c4 = 0; c4 < 4; ++c4) {
                        float4 wv = wk[c4];
                        acc[c4][0] += ha[kk] * wv.x; acc[c4][1] += ha[kk] * wv.y;
                        acc[c4][2] += ha[kk] * wv.z; acc[c4][3] += ha[kk] * wv.w;
                    }
                }
            }
        }
        __syncthreads();
        if (wave == 0 && lane < 32) {   // finalize pred, write it (coherent), accumulate loss
            float p = pbuf[lane] + pbuf[32 + lane] + pbuf[64 + lane] + pbuf[96 + lane] + pbias;
            int rr = lane & 15, dl = lane >> 4;
            int d = 2 * ht + dl;
            coh_st(&pred_buf[(size_t)(r0 + rr) * Dd + d], p);
            size_t ix = ((size_t)(r0 + rr) * (Tt - 1) + (t - 1)) * Dd + d;
            float e = (tgt[ix] - p) * msk[ix];
            lacc += e * e;
        }
        gbar();

        // ---- phase B: impute (coherent pred read), z_x, gates, h update ----
        for (int i = tid; i < 16 * Dd; i += NTHR) {
            int rr = i >> 6, d = i & 63;
            float xv = x[((size_t)(r0 + rr) * Tt + t) * Dd + d];
            float pv = coh_ld(&pred_buf[(size_t)(r0 + rr) * Dd + d]);
            xin[rr * XIN_STRIDE + d] = (xv == MISSINGV) ? pv : xv;
        }
        __syncthreads();
        do_zx();
        __syncthreads();
        store_zbuf();
        __syncthreads();
        combine();
        gbar();
    }

    // ---------------- epilogue ----------------
    if (wave == 0) {
        #pragma unroll
        for (int off = 16; off > 0; off >>= 1) lacc += __shfl_down(lacc, off);
        if (lane == 0) atomicAdd(ploss_acc, lacc);
    }
    gbar();

    if (bid == 0) {
        float* dwl = (float*)smem;                 // [512][10] staged dense_W
        __syncthreads();
        for (int i = tid; i < Hh * Cc; i += NTHR) dwl[i] = dW[i];
        __syncthreads();
        if (tid < Bb) {
            float a[Cc];
            #pragma unroll
            for (int c = 0; c < Cc; ++c) a[c] = db[c];
            for (int k = 0; k < Hh; ++k) {
                float hv = coh_ld(&h_buf[(size_t)tid * Hh + k]);
                #pragma unroll
                for (int c = 0; c < Cc; ++c) a[c] += hv * dwl[k * Cc + c];
            }
            float m = a[0];
            #pragma unroll
            for (int c = 1; c < Cc; ++c) m = fmaxf(m, a[c]);
            float s = 0.f;
            #pragma unroll
            for (int c = 0; c < Cc; ++c) s += expf(a[c] - m);
            float lse = m + logf(s);
            float lc = 0.f;
            #pragma unroll
            for (int c = 0; c < Cc; ++c) lc += lbl[tid * Cc + c] * (lse - a[c]);
            float pl = __hip_atomic_load(ploss_acc, __ATOMIC_RELAXED, __HIP_MEMORY_SCOPE_AGENT);
            float rg = __hip_atomic_load(reg_acc, __ATOMIC_RELAXED, __HIP_MEMORY_SCOPE_AGENT);
            out[tid] = lc + pl * (1.0f / (2088960.0f * 128.0f)) + 1e-4f * 0.5f * rg;
        }
    }
}

extern "C" void kernel_launch(void* const* d_in, const int* in_sizes, int n_in,
                              void* d_out, int out_size, void* d_ws, size_t ws_size,
                              hipStream_t stream) {
    const float* x     = (const float*)d_in[0];
    const float* tgt   = (const float*)d_in[1];
    const float* msk   = (const float*)d_in[2];
    const float* lbl   = (const float*)d_in[3];
    const float* W     = (const float*)d_in[4];
    const float* bias  = (const float*)d_in[5];
    const float* kern  = (const float*)d_in[6];
    const float* rkern = (const float*)d_in[7];
    const float* lbias = (const float*)d_in[8];
    const float* dW    = (const float*)d_in[9];
    const float* db    = (const float*)d_in[10];
    unsigned char* ws  = (unsigned char*)d_ws;

    hipMemsetAsync(d_ws, 0, 256, stream);
    perm_weights<<<4096, 256, 0, stream>>>(rkern, kern, (float*)(ws + WS_WT), (float*)(ws + WS_KT));
    ajrnn_persistent<<<NBLK, NTHR, 0, stream>>>(x, tgt, msk, lbl, W, bias, kern, rkern, lbias,
                                                dW, db, (float*)d_out, ws);
}

// Round 3
// 5999.281 us; speedup vs baseline: 4.8187x; 1.6334x over previous
//
#include <hip/hip_runtime.h>
#include <math.h>

// ---------------- problem dims ----------------
constexpr int Bb = 128, Tt = 256, Dd = 64, Hh = 512, Cc = 10;
constexpr float MISSINGV = 128.0f;

#define NBLK 256
#define NTHR 256
#define GRPSZ 32                                    // blocks per rt-group

typedef float v4f __attribute__((ext_vector_type(4)));

// ---------------- workspace layout (bytes) ----------------
constexpr size_t WS_GCNT  = 0;                      // global end-barrier counter
constexpr size_t WS_PLOSS = 128;                    // float pred-loss accumulator
constexpr size_t WS_REG   = 192;                    // float reg accumulator
constexpr size_t WS_GRP   = 256;                    // 8 group barrier lines x 256 B
constexpr size_t WS_PRED  = 4096;                   // pred_buf [128][64] f32 = 32768
constexpr size_t WS_H     = WS_PRED + 32768;        // h_buf [128][512] f32 = 262144
constexpr size_t WS_WT    = WS_H + 262144;          // wt_perm [32][512][64] f32 = 4 MB
constexpr size_t WS_KT    = WS_WT + 4194304;        // kt_perm [32][64][64] f32 = 512 KB
constexpr size_t WS_TOTAL = WS_KT + 524288;

// ---------------- LDS layout ----------------
constexpr int HT_STRIDE = 516;                      // hT [16][516] floats
constexpr int XIN_STRIDE = 68;
constexpr int ZB_RSTRIDE = 68;
constexpr int ZB_WSTRIDE = 16 * ZB_RSTRIDE;
constexpr size_t SM_HT    = 0;                      // 33024 B (aliased: zbuf / dense_W epilogue)
constexpr size_t SM_XIN   = 33024;                  // 4352 B (aliased: pbuf)
constexpr size_t SM_WCOL  = SM_XIN + 4352;          // [512][2] = 4096 B
constexpr size_t SM_RED   = SM_WCOL + 4096;         // 64 B
constexpr size_t SM_TOTAL = SM_RED + 64;            // 41536 B

// ---- coherent vector load (system-scope, bypasses L1/L2; served at IC) ----
// Batched: issue up to 8 loads, then ONE tied waitcnt -> one IC latency, not 8/32.
#define CLD4(dst, ptr) \
    asm volatile("global_load_dwordx4 %0, %1, off sc0 sc1" : "=v"(dst) : "v"(ptr))
#define CWAIT8(a0,a1,a2,a3,a4,a5,a6,a7) \
    asm volatile("s_waitcnt vmcnt(0)" \
        : "+v"(a0),"+v"(a1),"+v"(a2),"+v"(a3),"+v"(a4),"+v"(a5),"+v"(a6),"+v"(a7) :: "memory")
#define CWAIT1(a0) \
    asm volatile("s_waitcnt vmcnt(0)" : "+v"(a0) :: "memory")

__device__ __forceinline__ void coh_st(float* p, float v) {
    __hip_atomic_store(p, v, __ATOMIC_RELAXED, __HIP_MEMORY_SCOPE_AGENT);
}

// ---------------- weight permutation kernel ----------------
__global__ void perm_weights(const float* __restrict__ rk, const float* __restrict__ kern,
                             float* __restrict__ wtp, float* __restrict__ ktp) {
    int o = blockIdx.x * 256 + threadIdx.x;
    if (o < 32 * 512 * 64) {
        int uu = o & 63, k = (o >> 6) & 511, ht = o >> 15;
        int u = uu >> 2, g = uu & 3;
        wtp[o] = rk[k * 2048 + g * 512 + ht * 16 + u];
    }
    if (o < 32 * 64 * 64) {
        int uu = o & 63, d = (o >> 6) & 63, ht = o >> 12;
        int u = uu >> 2, g = uu & 3;
        ktp[o] = kern[d * 2048 + g * 512 + ht * 16 + u];
    }
}

__device__ __forceinline__ float sigmoidf_(float v) { return 1.0f / (1.0f + expf(-v)); }

// ---------------- persistent scan kernel ----------------
__launch_bounds__(NTHR, 1)
__global__ void ajrnn_persistent(
    const float* __restrict__ x, const float* __restrict__ tgt, const float* __restrict__ msk,
    const float* __restrict__ lbl, const float* __restrict__ W, const float* __restrict__ bias,
    const float* __restrict__ kern, const float* __restrict__ rkern, const float* __restrict__ lbias,
    const float* __restrict__ dW, const float* __restrict__ db,
    float* __restrict__ out, unsigned char* __restrict__ ws)
{
    __shared__ __align__(16) unsigned char smem[SM_TOTAL];
    float* hT    = (float*)(smem + SM_HT);
    float* xin   = (float*)(smem + SM_XIN);
    float* pbuf  = xin;                 // alias: phase-A only
    float* zbuf  = hT;                  // alias: phase-B only
    float* Wcol  = (float*)(smem + SM_WCOL);
    float* redsc = (float*)(smem + SM_RED);

    unsigned* endcnt = (unsigned*)(ws + WS_GCNT);
    float* ploss_acc = (float*)(ws + WS_PLOSS);
    float* reg_acc   = (float*)(ws + WS_REG);
    float* pred_buf  = (float*)(ws + WS_PRED);
    float* h_buf     = (float*)(ws + WS_H);
    const float* wt_perm = (const float*)(ws + WS_WT);
    const float* kt_perm = (const float*)(ws + WS_KT);

    const int tid = threadIdx.x;
    const int bid = blockIdx.x;
    const int rt = bid >> 5, ht = bid & 31;      // 8 row-tiles x 32 hidden-tiles
    const int r0 = rt * 16, j0 = ht * 16;
    const int wave = tid >> 6, lane = tid & 63;
    const int zr = lane & 15;
    const int uq = lane >> 4;
    const int cr = tid >> 4;
    const int cu = tid & 15;

    // ---- per-GROUP barrier: 32 blocks on a private cacheline (8 independent lines).
    // The batch dim is parallel: h_buf/pred_buf rows r0..r0+15 are produced AND
    // consumed only by this rt-group. No global sync until the end.
    unsigned* gcnt = (unsigned*)(ws + WS_GRP + (size_t)rt * 256);
    unsigned bar = 0;
    auto gbar = [&]() {
        bar += GRPSZ;
        __syncthreads();        // drains each wave's vmcnt before s_barrier
        if (tid == 0) {
            __builtin_amdgcn_s_waitcnt(0);
            __hip_atomic_fetch_add(gcnt, 1u, __ATOMIC_RELAXED, __HIP_MEMORY_SCOPE_AGENT);
            while (__hip_atomic_load(gcnt, __ATOMIC_RELAXED, __HIP_MEMORY_SCOPE_AGENT) < bar)
                __builtin_amdgcn_s_sleep(1);
        }
        __syncthreads();
    };

    // ---- setup: stage W columns (d = 2*ht, 2*ht+1), per-thread biases ----
    for (int i = tid; i < Hh * 2; i += NTHR)
        Wcol[i] = W[(i >> 1) * Dd + 2 * ht + (i & 1)];
    const float pbias = bias[2 * ht + ((lane >> 4) & 1)];
    const int ju = j0 + cu;
    const float lb0 = lbias[ju], lb1 = lbias[Hh + ju], lb2 = lbias[2 * Hh + ju], lb3 = lbias[3 * Hh + ju];

    // ---- L2 regularization ----
    {
        float rs = 0.f;
        const float* arrs[7] = {W, bias, kern, rkern, lbias, dW, db};
        const int lens[7] = {Hh * Dd, Dd, Dd * 4 * Hh, Hh * 4 * Hh, 4 * Hh, Hh * Cc, Cc};
        for (int a = 0; a < 7; ++a) {
            const float* p = arrs[a]; const int n = lens[a];
            for (int i = bid * NTHR + tid; i < n; i += NBLK * NTHR) { float v = p[i]; rs += v * v; }
        }
        #pragma unroll
        for (int off = 32; off > 0; off >>= 1) rs += __shfl_down(rs, off);
        if (lane == 0) redsc[wave] = rs;
        __syncthreads();
        if (tid == 0) atomicAdd(reg_acc, redsc[0] + redsc[1] + redsc[2] + redsc[3]);
        __syncthreads();
    }

    float c_reg = 0.f;
    float lacc = 0.f;
    float acc[4][4];

    const float* wtp = wt_perm + (size_t)ht * 512 * 64;
    const float* ktp = kt_perm + (size_t)ht * 64 * 64;

    auto do_zx = [&]() {
        const int dbeg = wave * 16;
        for (int d = dbeg; d < dbeg + 16; d += 4) {
            float4 xv4 = *(const float4*)&xin[zr * XIN_STRIDE + d];
            float xa[4] = {xv4.x, xv4.y, xv4.z, xv4.w};
            #pragma unroll
            for (int dd = 0; dd < 4; ++dd) {
                const float4* kd = (const float4*)&ktp[(size_t)(d + dd) * 64] + uq * 4;
                #pragma unroll
                for (int c4 = 0; c4 < 4; ++c4) {
                    float4 kv = kd[c4];
                    acc[c4][0] += xa[dd] * kv.x; acc[c4][1] += xa[dd] * kv.y;
                    acc[c4][2] += xa[dd] * kv.z; acc[c4][3] += xa[dd] * kv.w;
                }
            }
        }
    };
    auto store_zbuf = [&]() {
        #pragma unroll
        for (int c4 = 0; c4 < 4; ++c4) {
            float4 v = {acc[c4][0], acc[c4][1], acc[c4][2], acc[c4][3]};
            *(float4*)&zbuf[wave * ZB_WSTRIDE + zr * ZB_RSTRIDE + (uq * 4 + c4) * 4] = v;
        }
    };
    auto combine = [&]() {
        float4 z = {lb0, lb1, lb2, lb3};
        #pragma unroll
        for (int w = 0; w < 4; ++w) {
            float4 v = *(const float4*)&zbuf[w * ZB_WSTRIDE + cr * ZB_RSTRIDE + cu * 4];
            z.x += v.x; z.y += v.y; z.z += v.z; z.w += v.w;
        }
        float si = sigmoidf_(z.x), sf = sigmoidf_(z.y), so = sigmoidf_(z.w);
        c_reg = sf * c_reg + si * tanhf(z.z);
        float hv = so * tanhf(c_reg);
        coh_st(&h_buf[(size_t)(r0 + cr) * Hh + j0 + cu], hv);
    };

    // ---------------- step 0 ----------------
    for (int i = tid; i < 16 * Dd; i += NTHR) {
        int rr = i >> 6, d = i & 63;
        xin[rr * XIN_STRIDE + d] = x[((size_t)(r0 + rr) * Tt + 0) * Dd + d];
    }
    #pragma unroll
    for (int a = 0; a < 4; ++a)
        #pragma unroll
        for (int b2 = 0; b2 < 4; ++b2) acc[a][b2] = 0.f;
    __syncthreads();
    do_zx();
    __syncthreads();
    store_zbuf();
    __syncthreads();
    combine();
    gbar();

    // ---------------- steps t = 1..255 ----------------
    for (int t = 1; t < Tt; ++t) {
        // ---- phase A: batched coherent vector stage of h rows r0..r0+15 ----
        {
            v4f t0, t1, t2, t3, t4, t5, t6, t7;
            const float* hb = h_buf + (size_t)r0 * Hh;
            #define LD(tn, jj) { int i = tid + (jj) * NTHR; \
                const float* p = hb + ((i >> 7) * Hh) + ((i & 127) << 2); CLD4(tn, p); }
            LD(t0,0) LD(t1,1) LD(t2,2) LD(t3,3) LD(t4,4) LD(t5,5) LD(t6,6) LD(t7,7)
            #undef LD
            CWAIT8(t0, t1, t2, t3, t4, t5, t6, t7);
            #define ST(tn, jj) { int i = tid + (jj) * NTHR; \
                *(v4f*)&hT[(i >> 7) * HT_STRIDE + ((i & 127) << 2)] = tn; }
            ST(t0,0) ST(t1,1) ST(t2,2) ST(t3,3) ST(t4,4) ST(t5,5) ST(t6,6) ST(t7,7)
            #undef ST
        }
        __syncthreads();
        {   // pred partial over this wave's k-range
            const int pr = lane & 15, pdl = (lane >> 4) & 1, pkh = lane >> 5;
            float s = 0.f;
            const int kb = wave * 128 + pkh * 64;
            for (int k = kb; k < kb + 64; ++k)
                s += hT[pr * HT_STRIDE + k] * Wcol[k * 2 + pdl];
            s += __shfl_down(s, 32);
            if (lane < 32) pbuf[wave * 32 + lane] = s;
        }
        #pragma unroll
        for (int a = 0; a < 4; ++a)
            #pragma unroll
            for (int b2 = 0; b2 < 4; ++b2) acc[a][b2] = 0.f;
        {   // z_r over this wave's k-range
            const int kb = wave * 128;
            for (int k = kb; k < kb + 128; k += 4) {
                float4 hv4 = *(const float4*)&hT[zr * HT_STRIDE + k];
                float ha[4] = {hv4.x, hv4.y, hv4.z, hv4.w};
                #pragma unroll
                for (int kk = 0; kk < 4; ++kk) {
                    const float4* wk = (const float4*)&wtp[(size_t)(k + kk) * 64] + uq * 4;
                    #pragma unroll
                    for (int c4 = 0; c4 < 4; ++c4) {
                        float4 wv = wk[c4];
                        acc[c4][0] += ha[kk] * wv.x; acc[c4][1] += ha[kk] * wv.y;
                        acc[c4][2] += ha[kk] * wv.z; acc[c4][3] += ha[kk] * wv.w;
                    }
                }
            }
        }
        __syncthreads();
        if (wave == 0 && lane < 32) {
            float p = pbuf[lane] + pbuf[32 + lane] + pbuf[64 + lane] + pbuf[96 + lane] + pbias;
            int rr = lane & 15, dl = lane >> 4;
            int d = 2 * ht + dl;
            coh_st(&pred_buf[(size_t)(r0 + rr) * Dd + d], p);
            size_t ix = ((size_t)(r0 + rr) * (Tt - 1) + (t - 1)) * Dd + d;
            float e = (tgt[ix] - p) * msk[ix];
            lacc += e * e;
        }
        gbar();

        // ---- phase B: impute (batched coherent pred read), z_x, gates, h ----
        {
            int rr = tid >> 4, dq = (tid & 15) << 2;
            v4f pv;
            const float* pp = &pred_buf[(size_t)(r0 + rr) * Dd + dq];
            CLD4(pv, pp);
            float4 xv = *(const float4*)&x[((size_t)(r0 + rr) * Tt + t) * Dd + dq];
            CWAIT1(pv);
            float* xd = &xin[rr * XIN_STRIDE + dq];
            xd[0] = (xv.x == MISSINGV) ? pv.x : xv.x;
            xd[1] = (xv.y == MISSINGV) ? pv.y : xv.y;
            xd[2] = (xv.z == MISSINGV) ? pv.z : xv.z;
            xd[3] = (xv.w == MISSINGV) ? pv.w : xv.w;
        }
        __syncthreads();
        do_zx();
        __syncthreads();
        store_zbuf();
        __syncthreads();
        combine();
        gbar();
    }

    // ---------------- loss reduce + single global end barrier ----------------
    if (wave == 0) {
        #pragma unroll
        for (int off = 16; off > 0; off >>= 1) lacc += __shfl_down(lacc, off);
        if (lane == 0) atomicAdd(ploss_acc, lacc);
    }
    __syncthreads();
    if (tid == 0) {
        __builtin_amdgcn_s_waitcnt(0);
        __hip_atomic_fetch_add(endcnt, 1u, __ATOMIC_RELAXED, __HIP_MEMORY_SCOPE_AGENT);
    }

    if (bid == 0) {
        if (tid == 0) {
            while (__hip_atomic_load(endcnt, __ATOMIC_RELAXED, __HIP_MEMORY_SCOPE_AGENT) < NBLK)
                __builtin_amdgcn_s_sleep(8);
        }
        __syncthreads();
        float* dwl = (float*)smem;                 // [512][10] staged dense_W
        for (int i = tid; i < Hh * Cc; i += NTHR) dwl[i] = dW[i];
        __syncthreads();
        if (tid < Bb) {
            float a[Cc];
            #pragma unroll
            for (int c = 0; c < Cc; ++c) a[c] = db[c];
            const float* hrow = &h_buf[(size_t)tid * Hh];
            for (int kb = 0; kb < Hh; kb += 32) {
                v4f t0, t1, t2, t3, t4, t5, t6, t7;
                CLD4(t0, hrow + kb +  0); CLD4(t1, hrow + kb +  4);
                CLD4(t2, hrow + kb +  8); CLD4(t3, hrow + kb + 12);
                CLD4(t4, hrow + kb + 16); CLD4(t5, hrow + kb + 20);
                CLD4(t6, hrow + kb + 24); CLD4(t7, hrow + kb + 28);
                CWAIT8(t0, t1, t2, t3, t4, t5, t6, t7);
                float hv[32] = {t0.x,t0.y,t0.z,t0.w, t1.x,t1.y,t1.z,t1.w,
                                t2.x,t2.y,t2.z,t2.w, t3.x,t3.y,t3.z,t3.w,
                                t4.x,t4.y,t4.z,t4.w, t5.x,t5.y,t5.z,t5.w,
                                t6.x,t6.y,t6.z,t6.w, t7.x,t7.y,t7.z,t7.w};
                #pragma unroll
                for (int j = 0; j < 32; ++j)
                    #pragma unroll
                    for (int c = 0; c < Cc; ++c) a[c] += hv[j] * dwl[(kb + j) * Cc + c];
            }
            float m = a[0];
            #pragma unroll
            for (int c = 1; c < Cc; ++c) m = fmaxf(m, a[c]);
            float s = 0.f;
            #pragma unroll
            for (int c = 0; c < Cc; ++c) s += expf(a[c] - m);
            float lse = m + logf(s);
            float lc = 0.f;
            #pragma unroll
            for (int c = 0; c < Cc; ++c) lc += lbl[tid * Cc + c] * (lse - a[c]);
            float pl = __hip_atomic_load(ploss_acc, __ATOMIC_RELAXED, __HIP_MEMORY_SCOPE_AGENT);
            float rg = __hip_atomic_load(reg_acc, __ATOMIC_RELAXED, __HIP_MEMORY_SCOPE_AGENT);
            out[tid] = lc + pl * (1.0f / (2088960.0f * 128.0f)) + 1e-4f * 0.5f * rg;
        }
    }
}

extern "C" void kernel_launch(void* const* d_in, const int* in_sizes, int n_in,
                              void* d_out, int out_size, void* d_ws, size_t ws_size,
                              hipStream_t stream) {
    const float* x     = (const float*)d_in[0];
    const float* tgt   = (const float*)d_in[1];
    const float* msk   = (const float*)d_in[2];
    const float* lbl   = (const float*)d_in[3];
    const float* W     = (const float*)d_in[4];
    const float* bias  = (const float*)d_in[5];
    const float* kern  = (const float*)d_in[6];
    const float* rkern = (const float*)d_in[7];
    const float* lbias = (const float*)d_in[8];
    const float* dW    = (const float*)d_in[9];
    const float* db    = (const float*)d_in[10];
    unsigned char* ws  = (unsigned char*)d_ws;

    hipMemsetAsync(d_ws, 0, 4096, stream);
    perm_weights<<<4096, 256, 0, stream>>>(rkern, kern, (float*)(ws + WS_WT), (float*)(ws + WS_KT));
    ajrnn_persistent<<<NBLK, NTHR, 0, stream>>>(x, tgt, msk, lbl, W, bias, kern, rkern, lbias,
                                                dW, db, (float*)d_out, ws);
}

// Round 5
// 2272.661 us; speedup vs baseline: 12.7202x; 2.6398x over previous
//
#include <hip/hip_runtime.h>
#include <math.h>

// ---------------- problem dims ----------------
constexpr int Bb = 128, Tt = 256, Dd = 64, Hh = 512, Cc = 10;
constexpr float MISSINGV = 128.0f;

#define NBLK 256
#define NTHR 256
#define GRPSZ 32                                    // blocks per rt-group

typedef float v4f __attribute__((ext_vector_type(4)));
typedef float f4 __attribute__((ext_vector_type(4)));
typedef _Float16 half8 __attribute__((ext_vector_type(8)));
typedef _Float16 half4 __attribute__((ext_vector_type(4)));

// ---------------- workspace layout (bytes) ----------------
constexpr size_t WS_PLOSS = 128;                    // float pred-loss accumulator
constexpr size_t WS_REG   = 192;                    // float reg accumulator
constexpr size_t WS_GRP   = 256;                    // 8 group barrier lines x 256 B
constexpr size_t WS_H     = 4096;                   // h ping-pong [2][128][512] f32 = 524288
constexpr size_t WS_WT16  = WS_H + 524288;          // W^T fp16 [64 d][512 k] = 65536
constexpr size_t WS_BM16  = WS_WT16 + 65536;        // per-ht B fp16 [32][64 n][576 k] = 2359296

// ---------------- LDS layout (persistent kernel) ----------------
constexpr int HT_K = 584;                           // halfs per A row (576 + pad)
constexpr int PSTR = 68;                            // floats per predS/zS row
constexpr size_t SM_HT   = 0;                       // A fp16 [16][584] = 18688 B
constexpr size_t SM_PRED = 18688;                   // predS [16][68] f32 = 4352 B
constexpr size_t SM_ZS   = 23040;                   // zS    [16][68] f32 = 4352 B
constexpr size_t SM_RED  = 27392;                   // 64 B
constexpr size_t SM_TOTAL = 27456;

// ---- coherent vector load (sc0 sc1: bypasses L1/L2, served at IC) ----
#define CLD4(dst, ptr) \
    asm volatile("global_load_dwordx4 %0, %1, off sc0 sc1" : "=v"(dst) : "v"(ptr))
#define CWAIT8(a0,a1,a2,a3,a4,a5,a6,a7) \
    asm volatile("s_waitcnt vmcnt(0)" \
        : "+v"(a0),"+v"(a1),"+v"(a2),"+v"(a3),"+v"(a4),"+v"(a5),"+v"(a6),"+v"(a7) :: "memory")

__device__ __forceinline__ void coh_st(float* p, float v) {
    __hip_atomic_store(p, v, __ATOMIC_RELAXED, __HIP_MEMORY_SCOPE_AGENT);
}
__device__ __forceinline__ float sigmoidf_(float v) { return 1.0f / (1.0f + expf(-v)); }

__device__ __forceinline__ half8 cvt8(v4f a, v4f b) {
    half8 r;
    r[0]=(_Float16)a.x; r[1]=(_Float16)a.y; r[2]=(_Float16)a.z; r[3]=(_Float16)a.w;
    r[4]=(_Float16)b.x; r[5]=(_Float16)b.y; r[6]=(_Float16)b.z; r[7]=(_Float16)b.w;
    return r;
}

// ---------------- weight prep: fp16 pack ----------------
// WT16[d][k] = W[k][d]                  (pred B, K-major, shared by all blocks)
// BM16[ht][n][k]: n=u*4+g, col=g*512+ht*16+u; k<64 -> kernel[k][col], else rkernel[k-64][col]
__global__ void prep_weights(const float* __restrict__ rk, const float* __restrict__ kern,
                             const float* __restrict__ W,
                             _Float16* __restrict__ bm, _Float16* __restrict__ wt) {
    int o = blockIdx.x * 256 + threadIdx.x;
    if (o < 32 * 64 * 576) {
        int ht = o / 36864, rem = o % 36864, n = rem / 576, k = rem % 576;
        int u = n >> 2, g = n & 3, col = g * 512 + ht * 16 + u;
        float v = (k < 64) ? kern[k * 2048 + col] : rk[(k - 64) * 2048 + col];
        bm[o] = (_Float16)v;
    }
    if (o < 64 * 512) {
        int d = o >> 9, k = o & 511;
        wt[o] = (_Float16)W[k * 64 + d];
    }
}

// ---------------- persistent scan kernel ----------------
__launch_bounds__(NTHR, 1)
__global__ void ajrnn_persistent(
    const float* __restrict__ x, const float* __restrict__ tgt, const float* __restrict__ msk,
    const float* __restrict__ W, const float* __restrict__ bias,
    const float* __restrict__ kern, const float* __restrict__ rkern, const float* __restrict__ lbias,
    const float* __restrict__ dW, const float* __restrict__ db,
    unsigned char* __restrict__ ws)
{
    __shared__ __align__(16) unsigned char smem[SM_TOTAL];
    _Float16* hT = (_Float16*)(smem + SM_HT);       // A = [xin(0..63) | h(64..575)]
    float* predS = (float*)(smem + SM_PRED);
    float* zS    = (float*)(smem + SM_ZS);
    float* redsc = (float*)(smem + SM_RED);

    float* ploss_acc = (float*)(ws + WS_PLOSS);
    float* reg_acc   = (float*)(ws + WS_REG);
    float* h_base    = (float*)(ws + WS_H);         // [2][128][512]
    const _Float16* WT16g = (const _Float16*)(ws + WS_WT16);
    const _Float16* BM16g = (const _Float16*)(ws + WS_BM16);

    const int tid = threadIdx.x;
    const int bid = blockIdx.x;
    const int rt = bid >> 5, ht = bid & 31;         // 8 row-tiles x 32 hidden-tiles
    const int r0 = rt * 16, j0 = ht * 16;
    const int wave = tid >> 6, lane = tid & 63;
    const int lm = lane & 15;                       // MFMA A-row m / B-col within tile
    const int kq = (lane >> 4) * 8;                 // MFMA quad k offset
    const int cn = wave * 16 + lm;                  // this lane's global col (0..63)
    const int cr = tid >> 4, cu = tid & 15;         // gate-phase row/unit
    const int srr = tid >> 4, skc = (tid & 15) * 32;// stage row / k-chunk

    // per-GROUP barrier (32 blocks, private cacheline per rt-group)
    unsigned* gcnt = (unsigned*)(ws + WS_GRP + (size_t)rt * 256);
    unsigned bar = 0;
    auto gbar = [&]() {
        bar += GRPSZ;
        __syncthreads();        // each wave drains vmcnt before s_barrier
        if (tid == 0) {
            __builtin_amdgcn_s_waitcnt(0);
            __hip_atomic_fetch_add(gcnt, 1u, __ATOMIC_RELAXED, __HIP_MEMORY_SCOPE_AGENT);
            while (__hip_atomic_load(gcnt, __ATOMIC_RELAXED, __HIP_MEMORY_SCOPE_AGENT) < bar)
                __builtin_amdgcn_s_sleep(1);
        }
        __syncthreads();
    };

    // per-thread constants
    const float bvp = bias[cn];
    const int ju = j0 + cu;
    const float lb0 = lbias[ju], lb1 = lbias[Hh + ju], lb2 = lbias[2*Hh + ju], lb3 = lbias[3*Hh + ju];

    // ---- L2 regularization (each element counted exactly once across grid) ----
    {
        float rs = 0.f;
        const float* arrs[7] = {W, bias, kern, rkern, lbias, dW, db};
        const int lens[7] = {Hh*Dd, Dd, Dd*4*Hh, Hh*4*Hh, 4*Hh, Hh*Cc, Cc};
        for (int a = 0; a < 7; ++a) {
            const float* p = arrs[a]; const int n = lens[a];
            for (int i = bid * NTHR + tid; i < n; i += NBLK * NTHR) { float v = p[i]; rs += v * v; }
        }
        #pragma unroll
        for (int off = 32; off > 0; off >>= 1) rs += __shfl_down(rs, off);
        if (lane == 0) redsc[wave] = rs;
        __syncthreads();
        if (tid == 0) atomicAdd(reg_acc, redsc[0] + redsc[1] + redsc[2] + redsc[3]);
        __syncthreads();
    }

    float c_reg = 0.f;          // persistent cell state (row cr, unit cu)
    float lacc = 0.f;           // pred-loss accumulator (wave0 lanes<32)

    const _Float16* bmg = BM16g + ((size_t)ht * 64 + cn) * 576 + kq;   // z B row base
    const _Float16* wtg = WT16g + (size_t)cn * 512 + kq;               // pred B row base
    const _Float16* arow_h = hT + lm * HT_K + 64 + kq;                 // A h-part
    const _Float16* arow_z = hT + lm * HT_K + kq;                      // A full

    // z MFMA + gates + coherent h store into hw (ping-pong write buffer)
    auto z_phase = [&](float* hw) {
        f4 zacc = {0.f, 0.f, 0.f, 0.f};
        #pragma unroll
        for (int kk = 0; kk < 18; ++kk) {
            half8 av = *(const half8*)(arow_z + kk * 32);
            half8 bv = *(const half8*)(bmg + kk * 32);
            zacc = __builtin_amdgcn_mfma_f32_16x16x32_f16(av, bv, zacc, 0, 0, 0);
        }
        {
            const int prow = (lane >> 4) * 4;
            #pragma unroll
            for (int r = 0; r < 4; ++r) zS[(prow + r) * PSTR + cn] = zacc[r];
        }
        __syncthreads();
        float4 zv = *(const float4*)&zS[cr * PSTR + cu * 4];
        float si = sigmoidf_(zv.x + lb0), sf = sigmoidf_(zv.y + lb1), so = sigmoidf_(zv.w + lb3);
        c_reg = sf * c_reg + si * tanhf(zv.z + lb2);
        float hv = so * tanhf(c_reg);
        coh_st(&hw[(size_t)(r0 + cr) * Hh + j0 + cu], hv);
    };

    // ---------------- step 0 (t=0): xin = x0, h-part = 0, write hb[0] ----------------
    {
        half8 z8 = {0,0,0,0,0,0,0,0};
        _Float16* hrow = hT + srr * HT_K + 64 + skc;
        *(half8*)(hrow + 0) = z8; *(half8*)(hrow + 8) = z8;
        *(half8*)(hrow + 16) = z8; *(half8*)(hrow + 24) = z8;
        int rr = tid >> 4, dq = (tid & 15) * 4;
        float4 xv = *(const float4*)&x[((size_t)(r0 + rr) * Tt + 0) * Dd + dq];
        half4 xh; xh[0]=(_Float16)xv.x; xh[1]=(_Float16)xv.y; xh[2]=(_Float16)xv.z; xh[3]=(_Float16)xv.w;
        *(half4*)&hT[rr * HT_K + dq] = xh;
    }
    __syncthreads();
    z_phase(h_base);            // write buffer parity 0
    gbar();

    // ---------------- steps t = 1..255 (ONE barrier each; h ping-pong) ----------------
    for (int t = 1; t < Tt; ++t) {
        const float* hr = h_base + ((t - 1) & 1) * (size_t)65536;   // read state t
        float*       hw = h_base + (t & 1) * (size_t)65536;         // write state t+1
        // ---- stage h_t (batched coherent loads; pure r3-proven pattern) ----
        {
            const float* hp = &hr[(size_t)(r0 + srr) * Hh + skc];
            v4f a0,a1,a2,a3,a4,a5,a6,a7;
            CLD4(a0, hp+0);  CLD4(a1, hp+4);  CLD4(a2, hp+8);  CLD4(a3, hp+12);
            CLD4(a4, hp+16); CLD4(a5, hp+20); CLD4(a6, hp+24); CLD4(a7, hp+28);
            CWAIT8(a0,a1,a2,a3,a4,a5,a6,a7);
            _Float16* hrow = hT + srr * HT_K + 64 + skc;
            *(half8*)(hrow + 0)  = cvt8(a0, a1);
            *(half8*)(hrow + 8)  = cvt8(a2, a3);
            *(half8*)(hrow + 16) = cvt8(a4, a5);
            *(half8*)(hrow + 24) = cvt8(a6, a7);
        }
        float tg = 0.f, mkv = 0.f;
        if (wave == 0 && lane < 32) {       // loss targets (plain cached loads)
            size_t ix = ((size_t)(r0 + (lane & 15)) * (Tt - 1) + (t - 1)) * Dd + 2*ht + (lane >> 4);
            tg = tgt[ix]; mkv = msk[ix];
        }
        __syncthreads();

        // ---- full pred[16][64] via MFMA (redundant per block -> no pred exchange) ----
        {
            f4 pacc = {0.f, 0.f, 0.f, 0.f};
            #pragma unroll
            for (int kk = 0; kk < 16; ++kk) {
                half8 av = *(const half8*)(arow_h + kk * 32);
                half8 bv = *(const half8*)(wtg + kk * 32);
                pacc = __builtin_amdgcn_mfma_f32_16x16x32_f16(av, bv, pacc, 0, 0, 0);
            }
            const int prow = (lane >> 4) * 4;
            #pragma unroll
            for (int r = 0; r < 4; ++r) predS[(prow + r) * PSTR + cn] = pacc[r] + bvp;
        }
        __syncthreads();

        // ---- impute -> xin (fp16); accumulate this block's 2 loss cols ----
        {
            int rr = tid >> 4, dq = (tid & 15) * 4;
            float4 xv = *(const float4*)&x[((size_t)(r0 + rr) * Tt + t) * Dd + dq];
            float4 pv = *(const float4*)&predS[rr * PSTR + dq];
            half4 xh;
            xh[0] = (_Float16)((xv.x == MISSINGV) ? pv.x : xv.x);
            xh[1] = (_Float16)((xv.y == MISSINGV) ? pv.y : xv.y);
            xh[2] = (_Float16)((xv.z == MISSINGV) ? pv.z : xv.z);
            xh[3] = (_Float16)((xv.w == MISSINGV) ? pv.w : xv.w);
            *(half4*)&hT[rr * HT_K + dq] = xh;
            if (wave == 0 && lane < 32) {
                float p = predS[(lane & 15) * PSTR + 2*ht + (lane >> 4)];
                float e = (tg - p) * mkv;
                lacc += e * e;
            }
        }
        __syncthreads();

        z_phase(hw);
        gbar();
    }

    // ---------------- loss reduce; no end barrier (finalize is a separate kernel) ----
    if (wave == 0) {
        #pragma unroll
        for (int off = 16; off > 0; off >>= 1) lacc += __shfl_down(lacc, off);
        if (lane == 0) atomicAdd(ploss_acc, lacc);
    }
}

// ---------------- finalize: classification + total loss (1 block, 128 threads) ----------------
__global__ void finalize(const float* __restrict__ lbl, const float* __restrict__ dW,
                         const float* __restrict__ db, float* __restrict__ out,
                         unsigned char* __restrict__ ws)
{
    __shared__ float dwl[Hh * Cc];
    const int tid = threadIdx.x;
    for (int i = tid; i < Hh * Cc; i += 128) dwl[i] = dW[i];
    __syncthreads();
    const float* ploss_acc = (const float*)(ws + WS_PLOSS);
    const float* reg_acc   = (const float*)(ws + WS_REG);
    const float* h_last    = (const float*)(ws + WS_H) + 65536;   // parity 1 (t=255)

    float a[Cc];
    #pragma unroll
    for (int c = 0; c < Cc; ++c) a[c] = db[c];
    const float* hrow = &h_last[(size_t)tid * Hh];
    for (int kb = 0; kb < Hh; kb += 32) {
        v4f t0,t1,t2,t3,t4,t5,t6,t7;
        CLD4(t0, hrow+kb+0);  CLD4(t1, hrow+kb+4);
        CLD4(t2, hrow+kb+8);  CLD4(t3, hrow+kb+12);
        CLD4(t4, hrow+kb+16); CLD4(t5, hrow+kb+20);
        CLD4(t6, hrow+kb+24); CLD4(t7, hrow+kb+28);
        CWAIT8(t0,t1,t2,t3,t4,t5,t6,t7);
        float hv[32] = {t0.x,t0.y,t0.z,t0.w, t1.x,t1.y,t1.z,t1.w,
                        t2.x,t2.y,t2.z,t2.w, t3.x,t3.y,t3.z,t3.w,
                        t4.x,t4.y,t4.z,t4.w, t5.x,t5.y,t5.z,t5.w,
                        t6.x,t6.y,t6.z,t6.w, t7.x,t7.y,t7.z,t7.w};
        #pragma unroll
        for (int j = 0; j < 32; ++j)
            #pragma unroll
            for (int c = 0; c < Cc; ++c) a[c] += hv[j] * dwl[(kb + j) * Cc + c];
    }
    float m = a[0];
    #pragma unroll
    for (int c = 1; c < Cc; ++c) m = fmaxf(m, a[c]);
    float s = 0.f;
    #pragma unroll
    for (int c = 0; c < Cc; ++c) s += expf(a[c] - m);
    float lse = m + logf(s);
    float lc = 0.f;
    #pragma unroll
    for (int c = 0; c < Cc; ++c) lc += lbl[tid * Cc + c] * (lse - a[c]);
    float pl = __hip_atomic_load(ploss_acc, __ATOMIC_RELAXED, __HIP_MEMORY_SCOPE_AGENT);
    float rg = __hip_atomic_load(reg_acc, __ATOMIC_RELAXED, __HIP_MEMORY_SCOPE_AGENT);
    out[tid] = lc + pl * (1.0f / (2088960.0f * 128.0f)) + 1e-4f * 0.5f * rg;
}

extern "C" void kernel_launch(void* const* d_in, const int* in_sizes, int n_in,
                              void* d_out, int out_size, void* d_ws, size_t ws_size,
                              hipStream_t stream) {
    const float* x     = (const float*)d_in[0];
    const float* tgt   = (const float*)d_in[1];
    const float* msk   = (const float*)d_in[2];
    const float* lbl   = (const float*)d_in[3];
    const float* W     = (const float*)d_in[4];
    const float* bias  = (const float*)d_in[5];
    const float* kern  = (const float*)d_in[6];
    const float* rkern = (const float*)d_in[7];
    const float* lbias = (const float*)d_in[8];
    const float* dW    = (const float*)d_in[9];
    const float* db    = (const float*)d_in[10];
    unsigned char* ws  = (unsigned char*)d_ws;

    hipMemsetAsync(d_ws, 0, 4096, stream);
    prep_weights<<<4608, 256, 0, stream>>>(rkern, kern, W,
                                           (_Float16*)(ws + WS_BM16), (_Float16*)(ws + WS_WT16));
    ajrnn_persistent<<<NBLK, NTHR, 0, stream>>>(x, tgt, msk, W, bias, kern, rkern, lbias,
                                                dW, db, ws);
    finalize<<<1, 128, 0, stream>>>(lbl, dW, db, (float*)d_out, ws);
}

// Round 7
// 2116.254 us; speedup vs baseline: 13.6603x; 1.0739x over previous
//
#include <hip/hip_runtime.h>
#include <math.h>

// ---------------- problem dims ----------------
constexpr int Bb = 128, Tt = 256, Dd = 64, Hh = 512, Cc = 10;
constexpr float MISSINGV = 128.0f;

#define NBLK 256
#define NTHR 256
#define GRPSZ 32                                    // blocks per rt-group

typedef float v4f __attribute__((ext_vector_type(4)));
typedef float f4 __attribute__((ext_vector_type(4)));
typedef _Float16 half8 __attribute__((ext_vector_type(8)));
typedef _Float16 half4 __attribute__((ext_vector_type(4)));

// ---------------- workspace layout (bytes) ----------------
constexpr size_t WS_PLOSS = 128;                    // float pred-loss accumulator
constexpr size_t WS_REG   = 192;                    // float reg accumulator
constexpr size_t WS_FLG   = 256;                    // 8 groups x 256 B epoch-flag lines [256,2304)
constexpr size_t WS_H     = 4096;                   // h ping-pong [2][128][512] f32 = 524288
constexpr size_t WS_WT16  = WS_H + 524288;          // W^T fp16 [64 d][512 k] = 65536
constexpr size_t WS_BM16  = WS_WT16 + 65536;        // per-ht B fp16 [32][64 n][576 k] = 2359296

// ---------------- LDS layout (persistent kernel) ----------------
constexpr int HT_K = 584;                           // halfs per A row (576 + pad)
constexpr int PSTR = 68;                            // floats per predS/zS row
constexpr size_t SM_HT   = 0;                       // A fp16 [16][584] = 18688 B
constexpr size_t SM_PRED = 18688;                   // predS [16][68] f32 = 4352 B
constexpr size_t SM_ZS   = 23040;                   // zS    [16][68] f32 = 4352 B
constexpr size_t SM_RED  = 27392;                   // 64 B
constexpr size_t SM_TOTAL = 27456;

// ---- IC-coherent (sc0 sc1: bypass L1+L2, served at Infinity Cache) ----
#define CLD4(dst, ptr) \
    asm volatile("global_load_dwordx4 %0, %1, off sc0 sc1" : "=v"(dst) : "v"(ptr))
#define CWAIT8(a0,a1,a2,a3,a4,a5,a6,a7) \
    asm volatile("s_waitcnt vmcnt(0)" \
        : "+v"(a0),"+v"(a1),"+v"(a2),"+v"(a3),"+v"(a4),"+v"(a5),"+v"(a6),"+v"(a7) :: "memory")

__device__ __forceinline__ void coh_st(float* p, float v) {
    __hip_atomic_store(p, v, __ATOMIC_RELAXED, __HIP_MEMORY_SCOPE_AGENT);
}
__device__ __forceinline__ unsigned coh_ld_u(const unsigned* p) {
    return __hip_atomic_load(p, __ATOMIC_RELAXED, __HIP_MEMORY_SCOPE_AGENT);
}
__device__ __forceinline__ void coh_st_u(unsigned* p, unsigned v) {
    __hip_atomic_store(p, v, __ATOMIC_RELAXED, __HIP_MEMORY_SCOPE_AGENT);
}
__device__ __forceinline__ float sigmoidf_(float v) { return 1.0f / (1.0f + expf(-v)); }

__device__ __forceinline__ half8 cvt8(v4f a, v4f b) {
    half8 r;
    r[0]=(_Float16)a.x; r[1]=(_Float16)a.y; r[2]=(_Float16)a.z; r[3]=(_Float16)a.w;
    r[4]=(_Float16)b.x; r[5]=(_Float16)b.y; r[6]=(_Float16)b.z; r[7]=(_Float16)b.w;
    return r;
}

// ---------------- weight prep: fp16 pack ----------------
// WT16[d][k] = W[k][d]                  (pred B, K-major, shared by all blocks)
// BM16[ht][n][k]: n=u*4+g, col=g*512+ht*16+u; k<64 -> kernel[k][col], else rkernel[k-64][col]
__global__ void prep_weights(const float* __restrict__ rk, const float* __restrict__ kern,
                             const float* __restrict__ W,
                             _Float16* __restrict__ bm, _Float16* __restrict__ wt) {
    int o = blockIdx.x * 256 + threadIdx.x;
    if (o < 32 * 64 * 576) {
        int ht = o / 36864, rem = o % 36864, n = rem / 576, k = rem % 576;
        int u = n >> 2, g = n & 3, col = g * 512 + ht * 16 + u;
        float v = (k < 64) ? kern[k * 2048 + col] : rk[(k - 64) * 2048 + col];
        bm[o] = (_Float16)v;
    }
    if (o < 64 * 512) {
        int d = o >> 9, k = o & 511;
        wt[o] = (_Float16)W[k * 64 + d];
    }
}

// ---------------- persistent scan kernel ----------------
__launch_bounds__(NTHR, 1)
__global__ void ajrnn_persistent(
    const float* __restrict__ x, const float* __restrict__ tgt, const float* __restrict__ msk,
    const float* __restrict__ W, const float* __restrict__ bias,
    const float* __restrict__ kern, const float* __restrict__ rkern, const float* __restrict__ lbias,
    const float* __restrict__ dW, const float* __restrict__ db,
    unsigned char* __restrict__ ws)
{
    __shared__ __align__(16) unsigned char smem[SM_TOTAL];
    _Float16* hT = (_Float16*)(smem + SM_HT);       // A = [xin(0..63) | h(64..575)]
    float* predS = (float*)(smem + SM_PRED);
    float* zS    = (float*)(smem + SM_ZS);
    float* redsc = (float*)(smem + SM_RED);

    float* ploss_acc = (float*)(ws + WS_PLOSS);
    float* reg_acc   = (float*)(ws + WS_REG);
    float* h_base    = (float*)(ws + WS_H);         // [2][128][512]
    const _Float16* WT16g = (const _Float16*)(ws + WS_WT16);
    const _Float16* BM16g = (const _Float16*)(ws + WS_BM16);

    const int tid = threadIdx.x;
    const int bid = blockIdx.x;
    const int rt = bid >> 5, ht = bid & 31;         // 8 row-tiles x 32 hidden-tiles
    const int r0 = rt * 16, j0 = ht * 16;
    const int wave = tid >> 6, lane = tid & 63;
    const int lm = lane & 15;                       // MFMA A-row m / B-col within tile
    const int kq = (lane >> 4) * 8;                 // MFMA quad k offset
    const int cn = wave * 16 + lm;                  // this lane's global col (0..63)
    const int cr = tid >> 4, cu = tid & 15;         // gate-phase row/unit
    const int srr = tid >> 4, skc = (tid & 15) * 32;// stage row / k-chunk

    // ---- per-producer epoch flags (replaces the counting barrier) ----
    // flag[ht] == v  means:  block (rt,ht) has WRITTEN h[v] (its tile)  AND has
    // finished READING h[v-1].  "all flags >= t" therefore proves both that h[t]
    // is fully available and that h[t-1]'s parity buffer is dead -> ping-pong safe.
    // No atomics: 1 writer per word, read-only polls, monotone -> deadlock-free.
    unsigned* flg = (unsigned*)(ws + WS_FLG + (size_t)rt * 256);
    unsigned* myflag = flg + ht;
    auto flag_wait = [&](unsigned t) {              // all waves poll (no extra sync needed)
        for (;;) {
            unsigned f = coh_ld_u(&flg[lane & 31]);
            if (__all((int)(f >= t))) break;
            __builtin_amdgcn_s_sleep(1);
        }
    };

    // per-thread constants
    const float bvp = bias[cn];
    const int ju = j0 + cu;
    const float lb0 = lbias[ju], lb1 = lbias[Hh + ju], lb2 = lbias[2*Hh + ju], lb3 = lbias[3*Hh + ju];

    // ---- L2 regularization ----
    {
        float rs = 0.f;
        const float* arrs[7] = {W, bias, kern, rkern, lbias, dW, db};
        const int lens[7] = {Hh*Dd, Dd, Dd*4*Hh, Hh*4*Hh, 4*Hh, Hh*Cc, Cc};
        for (int a = 0; a < 7; ++a) {
            const float* p = arrs[a]; const int n = lens[a];
            for (int i = bid * NTHR + tid; i < n; i += NBLK * NTHR) { float v = p[i]; rs += v * v; }
        }
        #pragma unroll
        for (int off = 32; off > 0; off >>= 1) rs += __shfl_down(rs, off);
        if (lane == 0) redsc[wave] = rs;
        __syncthreads();
        if (tid == 0) atomicAdd(reg_acc, redsc[0] + redsc[1] + redsc[2] + redsc[3]);
        __syncthreads();
    }

    float c_reg = 0.f;          // persistent cell state (row cr, unit cu)
    float lacc = 0.f;           // pred-loss accumulator (wave0 lanes<32)

    const _Float16* bmg = BM16g + ((size_t)ht * 64 + cn) * 576 + kq;   // z B row base
    const _Float16* wtg = WT16g + (size_t)cn * 512 + kq;               // pred B row base
    const _Float16* arow_h = hT + lm * HT_K + 64 + kq;                 // A h-part
    const _Float16* arow_z = hT + lm * HT_K + kq;                      // A full

    // z MFMA + gates + coherent h store into hw (ping-pong write buffer)
    auto z_phase = [&](float* hw) {
        f4 zacc = {0.f, 0.f, 0.f, 0.f};
        #pragma unroll
        for (int kk = 0; kk < 18; ++kk) {
            half8 av = *(const half8*)(arow_z + kk * 32);
            half8 bv = *(const half8*)(bmg + kk * 32);
            zacc = __builtin_amdgcn_mfma_f32_16x16x32_f16(av, bv, zacc, 0, 0, 0);
        }
        {
            const int prow = (lane >> 4) * 4;
            #pragma unroll
            for (int r = 0; r < 4; ++r) zS[(prow + r) * PSTR + cn] = zacc[r];
        }
        __syncthreads();
        float4 zv = *(const float4*)&zS[cr * PSTR + cu * 4];
        float si = sigmoidf_(zv.x + lb0), sf = sigmoidf_(zv.y + lb1), so = sigmoidf_(zv.w + lb3);
        c_reg = sf * c_reg + si * tanhf(zv.z + lb2);
        float hv = so * tanhf(c_reg);
        coh_st(&hw[(size_t)(r0 + cr) * Hh + j0 + cu], hv);
    };

    // ---------------- step 0 (t=0): xin = x0, h-part = 0, write parity 0 ----------------
    {
        half8 z8 = {0,0,0,0,0,0,0,0};
        _Float16* hrow = hT + srr * HT_K + 64 + skc;
        *(half8*)(hrow + 0) = z8; *(half8*)(hrow + 8) = z8;
        *(half8*)(hrow + 16) = z8; *(half8*)(hrow + 24) = z8;
        int rr = tid >> 4, dq = (tid & 15) * 4;
        float4 xv = *(const float4*)&x[((size_t)(r0 + rr) * Tt + 0) * Dd + dq];
        half4 xh; xh[0]=(_Float16)xv.x; xh[1]=(_Float16)xv.y; xh[2]=(_Float16)xv.z; xh[3]=(_Float16)xv.w;
        *(half4*)&hT[rr * HT_K + dq] = xh;
    }
    __syncthreads();
    z_phase(h_base);
    __syncthreads();            // drains every wave's h-store vmcnt (compiler emits vmcnt(0) before s_barrier)
    if (tid == 0) coh_st_u(myflag, 1u);

    // ---------------- steps t = 1..255 (flag-synced; h ping-pong) ----------------
    for (int t = 1; t < Tt; ++t) {
        const float* hr = h_base + ((t - 1) & 1) * (size_t)65536;   // read state t
        float*       hw = h_base + (t & 1) * (size_t)65536;         // write state t+1

        // ---- prefetch step-t inputs (independent of other blocks' h) ----
        const int rr = tid >> 4, dq = (tid & 15) * 4;
        float4 xv = *(const float4*)&x[((size_t)(r0 + rr) * Tt + t) * Dd + dq];
        float tg = 0.f, mkv = 0.f;
        if (wave == 0 && lane < 32) {
            size_t ix = ((size_t)(r0 + (lane & 15)) * (Tt - 1) + (t - 1)) * Dd + 2*ht + (lane >> 4);
            tg = tgt[ix]; mkv = msk[ix];
        }

        // ---- wait for all producers of h[t] (read-only flag poll) ----
        flag_wait((unsigned)t);

        // ---- stage h_t (batched coherent loads; r3-proven pattern) ----
        {
            const float* hp = &hr[(size_t)(r0 + srr) * Hh + skc];
            v4f a0,a1,a2,a3,a4,a5,a6,a7;
            CLD4(a0, hp+0);  CLD4(a1, hp+4);  CLD4(a2, hp+8);  CLD4(a3, hp+12);
            CLD4(a4, hp+16); CLD4(a5, hp+20); CLD4(a6, hp+24); CLD4(a7, hp+28);
            CWAIT8(a0,a1,a2,a3,a4,a5,a6,a7);
            _Float16* hrow = hT + srr * HT_K + 64 + skc;
            *(half8*)(hrow + 0)  = cvt8(a0, a1);
            *(half8*)(hrow + 8)  = cvt8(a2, a3);
            *(half8*)(hrow + 16) = cvt8(a4, a5);
            *(half8*)(hrow + 24) = cvt8(a6, a7);
        }
        __syncthreads();

        // ---- full pred[16][64] via MFMA (redundant per block) ----
        {
            f4 pacc = {0.f, 0.f, 0.f, 0.f};
            #pragma unroll
            for (int kk = 0; kk < 16; ++kk) {
                half8 av = *(const half8*)(arow_h + kk * 32);
                half8 bv = *(const half8*)(wtg + kk * 32);
                pacc = __builtin_amdgcn_mfma_f32_16x16x32_f16(av, bv, pacc, 0, 0, 0);
            }
            const int prow = (lane >> 4) * 4;
            #pragma unroll
            for (int r = 0; r < 4; ++r) predS[(prow + r) * PSTR + cn] = pacc[r] + bvp;
        }
        __syncthreads();

        // ---- impute -> xin (fp16); accumulate this block's 2 loss cols ----
        {
            float4 pv = *(const float4*)&predS[rr * PSTR + dq];
            half4 xh;
            xh[0] = (_Float16)((xv.x == MISSINGV) ? pv.x : xv.x);
            xh[1] = (_Float16)((xv.y == MISSINGV) ? pv.y : xv.y);
            xh[2] = (_Float16)((xv.z == MISSINGV) ? pv.z : xv.z);
            xh[3] = (_Float16)((xv.w == MISSINGV) ? pv.w : xv.w);
            *(half4*)&hT[rr * HT_K + dq] = xh;
            if (wave == 0 && lane < 32) {
                float p = predS[(lane & 15) * PSTR + 2*ht + (lane >> 4)];
                float e = (tg - p) * mkv;
                lacc += e * e;
            }
        }
        __syncthreads();

        z_phase(hw);
        __syncthreads();        // all h[t+1] stores drained at coherence point
        if (tid == 0) coh_st_u(myflag, (unsigned)(t + 1));   // publish: wrote h[t+1], done reading h[t]
    }

    // ---------------- loss reduce; finalize is a separate kernel ----------------
    if (wave == 0) {
        #pragma unroll
        for (int off = 16; off > 0; off >>= 1) lacc += __shfl_down(lacc, off);
        if (lane == 0) atomicAdd(ploss_acc, lacc);
    }
}

// ---------------- finalize: classification + total loss (1 block, 128 threads) ----------------
__global__ void finalize(const float* __restrict__ lbl, const float* __restrict__ dW,
                         const float* __restrict__ db, float* __restrict__ out,
                         unsigned char* __restrict__ ws)
{
    __shared__ float dwl[Hh * Cc];
    const int tid = threadIdx.x;
    for (int i = tid; i < Hh * Cc; i += 128) dwl[i] = dW[i];
    __syncthreads();
    const float* ploss_acc = (const float*)(ws + WS_PLOSS);
    const float* reg_acc   = (const float*)(ws + WS_REG);
    const float* h_last    = (const float*)(ws + WS_H) + 65536;   // parity 1 (t=255)

    float a[Cc];
    #pragma unroll
    for (int c = 0; c < Cc; ++c) a[c] = db[c];
    const float* hrow = &h_last[(size_t)tid * Hh];
    for (int kb = 0; kb < Hh; kb += 32) {
        v4f t0,t1,t2,t3,t4,t5,t6,t7;
        CLD4(t0, hrow+kb+0);  CLD4(t1, hrow+kb+4);
        CLD4(t2, hrow+kb+8);  CLD4(t3, hrow+kb+12);
        CLD4(t4, hrow+kb+16); CLD4(t5, hrow+kb+20);
        CLD4(t6, hrow+kb+24); CLD4(t7, hrow+kb+28);
        CWAIT8(t0,t1,t2,t3,t4,t5,t6,t7);
        float hv[32] = {t0.x,t0.y,t0.z,t0.w, t1.x,t1.y,t1.z,t1.w,
                        t2.x,t2.y,t2.z,t2.w, t3.x,t3.y,t3.z,t3.w,
                        t4.x,t4.y,t4.z,t4.w, t5.x,t5.y,t5.z,t5.w,
                        t6.x,t6.y,t6.z,t6.w, t7.x,t7.y,t7.z,t7.w};
        #pragma unroll
        for (int j = 0; j < 32; ++j)
            #pragma unroll
            for (int c = 0; c < Cc; ++c) a[c] += hv[j] * dwl[(kb + j) * Cc + c];
    }
    float m = a[0];
    #pragma unroll
    for (int c = 1; c < Cc; ++c) m = fmaxf(m, a[c]);
    float s = 0.f;
    #pragma unroll
    for (int c = 0; c < Cc; ++c) s += expf(a[c] - m);
    float lse = m + logf(s);
    float lc = 0.f;
    #pragma unroll
    for (int c = 0; c < Cc; ++c) lc += lbl[tid * Cc + c] * (lse - a[c]);
    float pl = __hip_atomic_load(ploss_acc, __ATOMIC_RELAXED, __HIP_MEMORY_SCOPE_AGENT);
    float rg = __hip_atomic_load(reg_acc, __ATOMIC_RELAXED, __HIP_MEMORY_SCOPE_AGENT);
    out[tid] = lc + pl * (1.0f / (2088960.0f * 128.0f)) + 1e-4f * 0.5f * rg;
}

extern "C" void kernel_launch(void* const* d_in, const int* in_sizes, int n_in,
                              void* d_out, int out_size, void* d_ws, size_t ws_size,
                              hipStream_t stream) {
    const float* x     = (const float*)d_in[0];
    const float* tgt   = (const float*)d_in[1];
    const float* msk   = (const float*)d_in[2];
    const float* lbl   = (const float*)d_in[3];
    const float* W     = (const float*)d_in[4];
    const float* bias  = (const float*)d_in[5];
    const float* kern  = (const float*)d_in[6];
    const float* rkern = (const float*)d_in[7];
    const float* lbias = (const float*)d_in[8];
    const float* dW    = (const float*)d_in[9];
    const float* db    = (const float*)d_in[10];
    unsigned char* ws  = (unsigned char*)d_ws;

    hipMemsetAsync(d_ws, 0, 4096, stream);
    prep_weights<<<4608, 256, 0, stream>>>(rkern, kern, W,
                                           (_Float16*)(ws + WS_BM16), (_Float16*)(ws + WS_WT16));
    ajrnn_persistent<<<NBLK, NTHR, 0, stream>>>(x, tgt, msk, W, bias, kern, rkern, lbias,
                                                dW, db, ws);
    finalize<<<1, 128, 0, stream>>>(lbl, dW, db, (float*)d_out, ws);
}

// Round 9
// 2021.231 us; speedup vs baseline: 14.3025x; 1.0470x over previous
//
#include <hip/hip_runtime.h>
#include <math.h>

// ---------------- problem dims ----------------
constexpr int Bb = 128, Tt = 256, Dd = 64, Hh = 512, Cc = 10;
constexpr float MISSINGV = 128.0f;

#define NBLK 256
#define NTHR 256

typedef float v4f __attribute__((ext_vector_type(4)));
typedef float f4 __attribute__((ext_vector_type(4)));
typedef _Float16 half8 __attribute__((ext_vector_type(8)));
typedef _Float16 half4 __attribute__((ext_vector_type(4)));

// ---------------- workspace layout (bytes) ----------------
constexpr size_t WS_PLOSS = 128;                    // float pred-loss accumulator
constexpr size_t WS_REG   = 192;                    // float reg accumulator
constexpr size_t WS_FLG   = 256;                    // 8 groups x 512 B per-wave epoch flags [256,4352)
constexpr size_t WS_H     = 8192;                   // h fp16 ping-pong [2][128][512] = 262144 B
constexpr size_t WS_WT16  = WS_H + 262144;          // W^T fp16 [64 d][512 k] = 65536
constexpr size_t WS_BM16  = WS_WT16 + 65536;        // per-ht B fp16 [32][64 n][576 k] = 2359296

// ---------------- LDS layout ----------------
constexpr int XSTR = 72;                            // halfs per xin row (64 + pad)
constexpr int PSTR = 68;                            // floats per predS/zS row
constexpr size_t SM_XIN  = 0;                       // xin fp16 [16][72] = 2304 B
constexpr size_t SM_PRED = 2304;                    // predS [16][68] f32 = 4352 B
constexpr size_t SM_ZS   = 6656;                    // zS [16][68] f32 = 4352 B
constexpr size_t SM_RED  = 11008;                   // 64 B
constexpr size_t SM_TOTAL= 11072;

// ---- IC-coherent vector load with immediate offset (sc0 sc1: bypass L1+L2) ----
#define CLD4O(dst, base, OFF) \
    asm volatile("global_load_dwordx4 %0, %1, off offset:" OFF " sc0 sc1" : "=v"(dst) : "v"(base))
#define CWAIT16(a0,a1,a2,a3,a4,a5,a6,a7,a8,a9,aa,ab,ac,ad,ae,af) \
    asm volatile("s_waitcnt vmcnt(0)" \
        : "+v"(a0),"+v"(a1),"+v"(a2),"+v"(a3),"+v"(a4),"+v"(a5),"+v"(a6),"+v"(a7), \
          "+v"(a8),"+v"(a9),"+v"(aa),"+v"(ab),"+v"(ac),"+v"(ad),"+v"(ae),"+v"(af) :: "memory")

__device__ __forceinline__ unsigned coh_ld_u(const unsigned* p) {
    return __hip_atomic_load(p, __ATOMIC_RELAXED, __HIP_MEMORY_SCOPE_AGENT);
}
__device__ __forceinline__ void coh_st_u(unsigned* p, unsigned v) {
    __hip_atomic_store(p, v, __ATOMIC_RELAXED, __HIP_MEMORY_SCOPE_AGENT);
}
// fast, saturation-safe gate functions (abs err ~1e-6, fine vs 5.6e-2 threshold)
__device__ __forceinline__ float fsig(float v)  { return __builtin_amdgcn_rcpf(1.f + __expf(-v)); }
__device__ __forceinline__ float ftanh(float v) { float e = __expf(2.f*v); return 1.f - 2.f*__builtin_amdgcn_rcpf(e+1.f); }

// ---------------- weight prep: fp16 pack ----------------
// WT16[d][k] = W[k][d]; BM16[ht][n][k]: n=u*4+g, col=g*512+ht*16+u;
// k<64 -> kernel[k][col], else rkernel[k-64][col]
__global__ void prep_weights(const float* __restrict__ rk, const float* __restrict__ kern,
                             const float* __restrict__ W,
                             _Float16* __restrict__ bm, _Float16* __restrict__ wt) {
    int o = blockIdx.x * 256 + threadIdx.x;
    if (o < 32 * 64 * 576) {
        int ht = o / 36864, rem = o % 36864, n = rem / 576, k = rem % 576;
        int u = n >> 2, g = n & 3, col = g * 512 + ht * 16 + u;
        float v = (k < 64) ? kern[k * 2048 + col] : rk[(k - 64) * 2048 + col];
        bm[o] = (_Float16)v;
    }
    if (o < 64 * 512) {
        int d = o >> 9, k = o & 511;
        wt[o] = (_Float16)W[k * 64 + d];
    }
}

// ---------------- persistent scan kernel ----------------
__launch_bounds__(NTHR, 1)
__global__ void ajrnn_persistent(
    const float* __restrict__ x, const float* __restrict__ tgt, const float* __restrict__ msk,
    const float* __restrict__ W, const float* __restrict__ bias,
    const float* __restrict__ kern, const float* __restrict__ rkern, const float* __restrict__ lbias,
    const float* __restrict__ dW, const float* __restrict__ db,
    unsigned char* __restrict__ ws)
{
    __shared__ __align__(16) unsigned char smem[SM_TOTAL];
    _Float16* xinS = (_Float16*)(smem + SM_XIN);
    float* predS = (float*)(smem + SM_PRED);
    float* zS    = (float*)(smem + SM_ZS);
    float* redsc = (float*)(smem + SM_RED);

    float* ploss_acc = (float*)(ws + WS_PLOSS);
    float* reg_acc   = (float*)(ws + WS_REG);
    _Float16* h16h   = (_Float16*)(ws + WS_H);      // [2][128][512] halfs
    unsigned* h16u   = (unsigned*)(ws + WS_H);      // same, as packed uints [2][128][256]
    const _Float16* WT16g = (const _Float16*)(ws + WS_WT16);
    const _Float16* BM16g = (const _Float16*)(ws + WS_BM16);

    const int tid = threadIdx.x;
    const int bid = blockIdx.x;
    const int rt = bid >> 5, ht = bid & 31;         // 8 row-groups x 32 hidden-tiles
    const int r0 = rt * 16, j0 = ht * 16;
    const int wave = tid >> 6, lane = tid & 63;
    const int lm = lane & 15;                       // MFMA A-row m / B n-within-tile
    const int kq = (lane >> 4) * 8;                 // MFMA quad k offset
    const int cn = wave * 16 + lm;                  // this lane's global col (0..63)
    const int cr = tid >> 4, cu = tid & 15;         // gate-phase row/unit

    // ---- per-WAVE epoch flags: flg[ht*4+w] == v  means wave w of block (rt,ht)
    // has stored its rows of h[v] (vmcnt-drained) AND finished reading h[v-1].
    // all 128 flags >= t  =>  h[t] fully available AND h[t-1] buffer dead.
    // Single writer per word, monotone, no atomics -> deadlock-free.
    unsigned* flg = (unsigned*)(ws + WS_FLG + (size_t)rt * 512);
    auto flag_wait = [&](unsigned t) {
        for (;;) {
            unsigned f0 = coh_ld_u(&flg[lane]);
            unsigned f1 = coh_ld_u(&flg[64 + lane]);
            if (__all((int)(f0 >= t && f1 >= t))) break;
            __builtin_amdgcn_s_sleep(1);
        }
    };

    // per-thread constants
    const float bvp = bias[cn];
    const int ju = j0 + cu;
    const float lb0 = lbias[ju], lb1 = lbias[Hh + ju], lb2 = lbias[2*Hh + ju], lb3 = lbias[3*Hh + ju];

    // ---- L2 regularization ----
    {
        float rs = 0.f;
        const float* arrs[7] = {W, bias, kern, rkern, lbias, dW, db};
        const int lens[7] = {Hh*Dd, Dd, Dd*4*Hh, Hh*4*Hh, 4*Hh, Hh*Cc, Cc};
        for (int a = 0; a < 7; ++a) {
            const float* p = arrs[a]; const int n = lens[a];
            for (int i = bid * NTHR + tid; i < n; i += NBLK * NTHR) { float v = p[i]; rs += v * v; }
        }
        #pragma unroll
        for (int off = 32; off > 0; off >>= 1) rs += __shfl_down(rs, off);
        if (lane == 0) redsc[wave] = rs;
        __syncthreads();
        if (tid == 0) atomicAdd(reg_acc, redsc[0] + redsc[1] + redsc[2] + redsc[3]);
        __syncthreads();
    }

    // ---- B matrices permanently in VGPRs (1 block/CU, 1 wave/SIMD -> ~512 regs OK) ----
    half8 b_z[18], b_p[16];
    {
        const _Float16* bmg = BM16g + ((size_t)ht * 64 + cn) * 576 + kq;
        const _Float16* wtg = WT16g + (size_t)cn * 512 + kq;
        #pragma unroll
        for (int kk = 0; kk < 18; ++kk) b_z[kk] = *(const half8*)(bmg + kk * 32);
        #pragma unroll
        for (int kk = 0; kk < 16; ++kk) b_p[kk] = *(const half8*)(wtg + kk * 32);
    }

    float c_reg = 0.f;          // persistent cell state (row cr, unit cu)
    float lacc = 0.f;           // pred-loss accumulator (wave0 lanes<32)

    // gates + packed-fp16 h store + per-wave flag publish
    auto gates_pub = [&](f4 zacc, unsigned* hwu, unsigned tpub) {
        const int prow = (lane >> 4) * 4;
        #pragma unroll
        for (int r = 0; r < 4; ++r) zS[(prow + r) * PSTR + cn] = zacc[r];
        __syncthreads();
        float4 zv = *(const float4*)&zS[cr * PSTR + cu * 4];
        float si = fsig(zv.x + lb0), sf = fsig(zv.y + lb1), so = fsig(zv.w + lb3);
        c_reg = sf * c_reg + si * ftanh(zv.z + lb2);
        float hv = so * ftanh(c_reg);
        float hv1 = __shfl_down(hv, 1);
        if (!(cu & 1)) {
            auto p = __builtin_amdgcn_cvt_pkrtz(hv, hv1);   // __fp16 ext_vector(2)
            coh_st_u(&hwu[(size_t)(r0 + cr) * 256 + ((j0 + cu) >> 1)],
                     __builtin_bit_cast(unsigned, p));
        }
        asm volatile("s_waitcnt vmcnt(0)" ::: "memory");   // this wave's stores are at IC
        if (lane == 0) coh_st_u(&flg[ht * 4 + wave], tpub);
    };

    // ---------------- step 0 (t=0): z = x0 @ kernel only (h0=0), write parity 0 ----------------
    {
        const int rr = tid >> 4, dq = (tid & 15) * 4;
        float4 xv = *(const float4*)&x[((size_t)(r0 + rr) * Tt + 0) * Dd + dq];
        half4 xh; xh[0]=(_Float16)xv.x; xh[1]=(_Float16)xv.y; xh[2]=(_Float16)xv.z; xh[3]=(_Float16)xv.w;
        *(half4*)&xinS[rr * XSTR + dq] = xh;
        __syncthreads();
        half8 ax0 = *(const half8*)&xinS[lm * XSTR + kq];
        half8 ax1 = *(const half8*)&xinS[lm * XSTR + 32 + kq];
        f4 zacc = {0.f, 0.f, 0.f, 0.f};
        zacc = __builtin_amdgcn_mfma_f32_16x16x32_f16(ax0, b_z[0], zacc, 0, 0, 0);
        zacc = __builtin_amdgcn_mfma_f32_16x16x32_f16(ax1, b_z[1], zacc, 0, 0, 0);
        gates_pub(zacc, h16u, 1u);
    }

    // ---------------- steps t = 1..255 ----------------
    for (int t = 1; t < Tt; ++t) {
        const _Float16* hr = h16h + ((t - 1) & 1) * (size_t)65536;   // read h[t]
        unsigned*       hwu = h16u + (t & 1) * (size_t)32768;        // write h[t+1]

        // ---- prefetch step-t inputs (off critical path) ----
        const int rr = tid >> 4, dq = (tid & 15) * 4;
        float4 xv = *(const float4*)&x[((size_t)(r0 + rr) * Tt + t) * Dd + dq];
        float tg = 0.f, mkv = 0.f;
        if (wave == 0 && lane < 32) {
            size_t ix = ((size_t)(r0 + (lane & 15)) * (Tt - 1) + (t - 1)) * Dd + 2*ht + (lane >> 4);
            tg = tgt[ix]; mkv = msk[ix];
        }

        // ---- wait for all 128 producer-wave flags of h[t] ----
        flag_wait((unsigned)t);

        // ---- per-lane direct h fragment loads (one IC window, no LDS staging) ----
        const char* hbp = (const char*)(hr + (size_t)(r0 + lm) * 512 + kq);
        v4f a0,a1,a2,a3,a4,a5,a6,a7,a8,a9,aa,ab,ac,ad,ae,af;
        CLD4O(a0, hbp, "0");   CLD4O(a1, hbp, "64");  CLD4O(a2, hbp, "128"); CLD4O(a3, hbp, "192");
        CLD4O(a4, hbp, "256"); CLD4O(a5, hbp, "320"); CLD4O(a6, hbp, "384"); CLD4O(a7, hbp, "448");
        CLD4O(a8, hbp, "512"); CLD4O(a9, hbp, "576"); CLD4O(aa, hbp, "640"); CLD4O(ab, hbp, "704");
        CLD4O(ac, hbp, "768"); CLD4O(ad, hbp, "832"); CLD4O(ae, hbp, "896"); CLD4O(af, hbp, "960");
        CWAIT16(a0,a1,a2,a3,a4,a5,a6,a7,a8,a9,aa,ab,ac,ad,ae,af);
        half8 ah[16];
        ah[0]=__builtin_bit_cast(half8,a0);  ah[1]=__builtin_bit_cast(half8,a1);
        ah[2]=__builtin_bit_cast(half8,a2);  ah[3]=__builtin_bit_cast(half8,a3);
        ah[4]=__builtin_bit_cast(half8,a4);  ah[5]=__builtin_bit_cast(half8,a5);
        ah[6]=__builtin_bit_cast(half8,a6);  ah[7]=__builtin_bit_cast(half8,a7);
        ah[8]=__builtin_bit_cast(half8,a8);  ah[9]=__builtin_bit_cast(half8,a9);
        ah[10]=__builtin_bit_cast(half8,aa); ah[11]=__builtin_bit_cast(half8,ab);
        ah[12]=__builtin_bit_cast(half8,ac); ah[13]=__builtin_bit_cast(half8,ad);
        ah[14]=__builtin_bit_cast(half8,ae); ah[15]=__builtin_bit_cast(half8,af);

        // ---- pred[16][64] = h @ W^T via MFMA, all operands in registers ----
        {
            f4 pacc = {0.f, 0.f, 0.f, 0.f};
            #pragma unroll
            for (int kk = 0; kk < 16; ++kk)
                pacc = __builtin_amdgcn_mfma_f32_16x16x32_f16(ah[kk], b_p[kk], pacc, 0, 0, 0);
            const int prow = (lane >> 4) * 4;
            #pragma unroll
            for (int r = 0; r < 4; ++r) predS[(prow + r) * PSTR + cn] = pacc[r] + bvp;
        }
        __syncthreads();

        // ---- impute -> xin LDS (fp16); accumulate this block's 2 loss cols ----
        {
            float4 pv = *(const float4*)&predS[rr * PSTR + dq];
            half4 xh;
            xh[0] = (_Float16)((xv.x == MISSINGV) ? pv.x : xv.x);
            xh[1] = (_Float16)((xv.y == MISSINGV) ? pv.y : xv.y);
            xh[2] = (_Float16)((xv.z == MISSINGV) ? pv.z : xv.z);
            xh[3] = (_Float16)((xv.w == MISSINGV) ? pv.w : xv.w);
            *(half4*)&xinS[rr * XSTR + dq] = xh;
            if (wave == 0 && lane < 32) {
                float p = predS[(lane & 15) * PSTR + 2*ht + (lane >> 4)];
                float e = (tg - p) * mkv;
                lacc += e * e;
            }
        }
        __syncthreads();

        // ---- z = [xin | h] @ B : 16 reg-sourced + 2 LDS-sourced MFMAs ----
        {
            half8 ax0 = *(const half8*)&xinS[lm * XSTR + kq];
            half8 ax1 = *(const half8*)&xinS[lm * XSTR + 32 + kq];
            f4 zacc = {0.f, 0.f, 0.f, 0.f};
            #pragma unroll
            for (int kk = 0; kk < 16; ++kk)
                zacc = __builtin_amdgcn_mfma_f32_16x16x32_f16(ah[kk], b_z[kk + 2], zacc, 0, 0, 0);
            zacc = __builtin_amdgcn_mfma_f32_16x16x32_f16(ax0, b_z[0], zacc, 0, 0, 0);
            zacc = __builtin_amdgcn_mfma_f32_16x16x32_f16(ax1, b_z[1], zacc, 0, 0, 0);
            gates_pub(zacc, hwu, (unsigned)(t + 1));
        }
    }

    // ---------------- loss reduce; finalize is a separate kernel ----------------
    if (wave == 0) {
        #pragma unroll
        for (int off = 16; off > 0; off >>= 1) lacc += __shfl_down(lacc, off);
        if (lane == 0) atomicAdd(ploss_acc, lacc);
    }
}

// ---------------- finalize: classification + total loss (1 block, 128 threads) ----------------
// Separate dispatch: kernel-boundary ordering makes the persistent kernel's IC-resident
// stores visible to plain cached loads here.
__global__ void finalize(const float* __restrict__ lbl, const float* __restrict__ dW,
                         const float* __restrict__ db, float* __restrict__ out,
                         unsigned char* __restrict__ ws)
{
    __shared__ float dwl[Hh * Cc];
    const int tid = threadIdx.x;
    for (int i = tid; i < Hh * Cc; i += 128) dwl[i] = dW[i];
    __syncthreads();
    const float* ploss_acc = (const float*)(ws + WS_PLOSS);
    const float* reg_acc   = (const float*)(ws + WS_REG);
    const _Float16* h_last = (const _Float16*)(ws + WS_H) + 65536;   // parity 1 (t=255)

    if (tid < Bb) {
        float a[Cc];
        #pragma unroll
        for (int c = 0; c < Cc; ++c) a[c] = db[c];
        const _Float16* hrow = h_last + (size_t)tid * Hh;
        for (int k = 0; k < Hh; k += 8) {
            half8 hh = *(const half8*)(hrow + k);
            #pragma unroll
            for (int j = 0; j < 8; ++j) {
                float hv = (float)hh[j];
                #pragma unroll
                for (int c = 0; c < Cc; ++c) a[c] += hv * dwl[(k + j) * Cc + c];
            }
        }
        float m = a[0];
        #pragma unroll
        for (int c = 1; c < Cc; ++c) m = fmaxf(m, a[c]);
        float s = 0.f;
        #pragma unroll
        for (int c = 0; c < Cc; ++c) s += expf(a[c] - m);
        float lse = m + logf(s);
        float lc = 0.f;
        #pragma unroll
        for (int c = 0; c < Cc; ++c) lc += lbl[tid * Cc + c] * (lse - a[c]);
        float pl = ploss_acc[0];
        float rg = reg_acc[0];
        out[tid] = lc + pl * (1.0f / (2088960.0f * 128.0f)) + 1e-4f * 0.5f * rg;
    }
}

extern "C" void kernel_launch(void* const* d_in, const int* in_sizes, int n_in,
                              void* d_out, int out_size, void* d_ws, size_t ws_size,
                              hipStream_t stream) {
    const float* x     = (const float*)d_in[0];
    const float* tgt   = (const float*)d_in[1];
    const float* msk   = (const float*)d_in[2];
    const float* lbl   = (const float*)d_in[3];
    const float* W     = (const float*)d_in[4];
    const float* bias  = (const float*)d_in[5];
    const float* kern  = (const float*)d_in[6];
    const float* rkern = (const float*)d_in[7];
    const float* lbias = (const float*)d_in[8];
    const float* dW    = (const float*)d_in[9];
    const float* db    = (const float*)d_in[10];
    unsigned char* ws  = (unsigned char*)d_ws;

    (void)hipMemsetAsync(d_ws, 0, 8192, stream);
    prep_weights<<<4608, 256, 0, stream>>>(rkern, kern, W,
                                           (_Float16*)(ws + WS_BM16), (_Float16*)(ws + WS_WT16));
    ajrnn_persistent<<<NBLK, NTHR, 0, stream>>>(x, tgt, msk, W, bias, kern, rkern, lbias,
                                                dW, db, ws);
    finalize<<<1, 128, 0, stream>>>(lbl, dW, db, (float*)d_out, ws);
}